// Round 1
// baseline (399.942 us; speedup 1.0000x reference)
//
#include <hip/hip_runtime.h>
#include <hip/hip_bf16.h>

#define N_NODES 100000
#define N_EDGES 1600000
#define N_TOT   (N_EDGES + N_NODES)   // edges + self loops
#define F_IN    256
#define F1      64     // H1*C1
#define H1      8
#define C1      8
#define F2      32
#define SLOPE   0.2f
#define CHUNK   2048
#define NCH     ((N_NODES + CHUNK - 1) / CHUNK)   // 49

#define NB_G    ((N_NODES + 255) / 256)           // 391 gemm blocks
#define NB_H    ((N_EDGES + 255) / 256)           // 6250 hist blocks (real edges only)

#define SLICES  8                                  // one dst-slice per XCD
#define SL_W    ((N_NODES + SLICES - 1) / SLICES)  // 12500 nodes/slice
#define CH_E    16384                              // edges per scatter chunk
#define NCHUNK  ((N_EDGES + CH_E - 1) / CH_E)      // 98

typedef unsigned int  uint;
typedef unsigned short ushort;
typedef __attribute__((ext_vector_type(8))) short bf16x8;
typedef __attribute__((ext_vector_type(4))) float f32x4;

__device__ inline ushort f2bf(float f) {               // RNE float->bf16
    uint u = __float_as_uint(f);
    uint r = u + 0x7fffu + ((u >> 16) & 1u);
    return (ushort)(r >> 16);
}
__device__ inline float bflo(uint u) { return __uint_as_float(u << 16); }
__device__ inline float bfhi(uint u) { return __uint_as_float(u & 0xffff0000u); }
__device__ inline uint pk2bf(float a, float b) {
    __hip_bfloat162 h = __float22bfloat162_rn(make_float2(a, b));
    union { __hip_bfloat162 h; uint u; } cv; cv.h = h;
    return cv.u;
}

// ---------------------------------------------------------------------------
// K1 fused: blocks [0,NB_G) = MFMA gemm (h1 = x@W1 + s1/d1 dots);
// blocks [NB_G, NB_G+NB_H) = hist+rank over REAL edges only (self-loops get
// reserved slot 0 per segment -- no atomic needed for them). Device-scope
// atomic rank is ~20 Gops/s structural; the gemm hides under the atomic
// window.
// ---------------------------------------------------------------------------
__global__ __launch_bounds__(256) void k_gemm1_hist(
        const float* __restrict__ x, const float* __restrict__ W1,
        const float* __restrict__ as1, const float* __restrict__ ad1,
        const int* __restrict__ ei,
        ushort* __restrict__ h1b, float* __restrict__ s1, float* __restrict__ d1,
        int* __restrict__ cnt, int* __restrict__ rank) {
    __shared__ union {
        ushort B[F_IN * F1];        // 32 KB: W1 bf16, idx = ((k>>3)*64+n)*8 + (k&7)
        ushort S[4][64][66];        // 33.8 KB: per-wave h staging (pad 66)
    } sm;
    const int tid = threadIdx.x;

    if (blockIdx.x >= NB_G) {                      // ---- hist + rank part ----
        const int e = (blockIdx.x - NB_G) * 256 + tid;
        if (e < N_EDGES)
            rank[e] = atomicAdd(cnt + ei[N_EDGES + e], 1);
        return;
    }

    // ---- MFMA gemm part ----
    for (int i = 0; i < 64; ++i) {                 // stage + swizzle W1
        const int e = i * 256 + tid;               // e = k*64 + n
        const int k = e >> 6, n = e & 63;
        sm.B[((k >> 3) * 64 + n) * 8 + (k & 7)] = f2bf(W1[e]);
    }
    __syncthreads();

    const int wave = tid >> 6, lane = tid & 63;
    const int q = lane >> 4, ln = lane & 15;
    const int rowbase = blockIdx.x * 256 + wave * 64;

    f32x4 acc[4][4];
#pragma unroll
    for (int mt = 0; mt < 4; ++mt)
#pragma unroll
        for (int nt = 0; nt < 4; ++nt) acc[mt][nt] = (f32x4){0.f, 0.f, 0.f, 0.f};

    int rows[4];
#pragma unroll
    for (int mt = 0; mt < 4; ++mt) {
        const int r = rowbase + mt * 16 + ln;
        rows[mt] = r < N_NODES ? r : N_NODES - 1;
    }

    for (int t = 0; t < 8; ++t) {                  // K-loop: 8 x 32
        bf16x8 bfr[4];
#pragma unroll
        for (int nt = 0; nt < 4; ++nt)
            bfr[nt] = *(const bf16x8*)&sm.B[((t * 4 + q) * 64 + nt * 16 + ln) * 8];
#pragma unroll
        for (int mt = 0; mt < 4; ++mt) {
            const float4* ap = (const float4*)(x + (size_t)rows[mt] * F_IN + t * 32 + q * 8);
            const float4 a0 = ap[0], a1 = ap[1];
            uint4 au = make_uint4(pk2bf(a0.x, a0.y), pk2bf(a0.z, a0.w),
                                  pk2bf(a1.x, a1.y), pk2bf(a1.z, a1.w));
            bf16x8 af = *(bf16x8*)&au;
#pragma unroll
            for (int nt = 0; nt < 4; ++nt)
                acc[mt][nt] = __builtin_amdgcn_mfma_f32_16x16x32_bf16(
                                  af, bfr[nt], acc[mt][nt], 0, 0, 0);
        }
    }
    __syncthreads();

    // stage h (bf16): C/D layout col=lane&15, row=q*4+r
#pragma unroll
    for (int mt = 0; mt < 4; ++mt)
#pragma unroll
        for (int nt = 0; nt < 4; ++nt)
#pragma unroll
            for (int r = 0; r < 4; ++r)
                sm.S[wave][mt * 16 + q * 4 + r][nt * 16 + ln] = f2bf(acc[mt][nt][r]);
    __syncthreads();

    const int node = rowbase + lane;
    if (node >= N_NODES) return;
    const uint* srow = (const uint*)&sm.S[wave][lane][0];
    float sacc[H1], dacc[H1];
#pragma unroll
    for (int h = 0; h < H1; ++h) { sacc[h] = 0.f; dacc[h] = 0.f; }
    uint4* hout = (uint4*)(h1b + (size_t)node * F1);
#pragma unroll
    for (int p4 = 0; p4 < 8; ++p4) {               // p4 == head index
        const uint u0 = srow[p4 * 4 + 0], u1 = srow[p4 * 4 + 1];
        const uint u2 = srow[p4 * 4 + 2], u3 = srow[p4 * 4 + 3];
        hout[p4] = make_uint4(u0, u1, u2, u3);
        const float c[8] = {bflo(u0), bfhi(u0), bflo(u1), bfhi(u1),
                            bflo(u2), bfhi(u2), bflo(u3), bfhi(u3)};
#pragma unroll
        for (int j = 0; j < 8; ++j) {
            sacc[p4] += c[j] * as1[p4 * 8 + j];
            dacc[p4] += c[j] * ad1[p4 * 8 + j];
        }
    }
    float4* s4 = (float4*)(s1 + (size_t)node * H1);
    float4* d4 = (float4*)(d1 + (size_t)node * H1);
    s4[0] = make_float4(sacc[0], sacc[1], sacc[2], sacc[3]);
    s4[1] = make_float4(sacc[4], sacc[5], sacc[6], sacc[7]);
    d4[0] = make_float4(dacc[0], dacc[1], dacc[2], dacc[3]);
    d4[1] = make_float4(dacc[4], dacc[5], dacc[6], dacc[7]);
}

// ---------------------------------------------------------------------------
// Scan: per-chunk scan (a) with +1 per node (reserved self-loop slot), then
// fused chunk-prefix + add + self-loop emit (c2).
// ---------------------------------------------------------------------------
__global__ __launch_bounds__(256) void k_scan_a(
        const int* __restrict__ cnt, int* __restrict__ row_ptr,
        int* __restrict__ bsum) {
    __shared__ int sdata[256];
    const int tid = threadIdx.x;
    const int base = blockIdx.x * CHUNK + tid * 8;
    int v[8];
    int tot = 0;
#pragma unroll
    for (int j = 0; j < 8; ++j) {
        v[j] = (base + j < N_NODES) ? cnt[base + j] + 1 : 0;   // +1 = self loop
        tot += v[j];
    }
    sdata[tid] = tot;
    __syncthreads();
    for (int off = 1; off < 256; off <<= 1) {
        int t = (tid >= off) ? sdata[tid - off] : 0;
        __syncthreads();
        sdata[tid] += t;
        __syncthreads();
    }
    int run = sdata[tid] - tot;
#pragma unroll
    for (int j = 0; j < 8; ++j) {
        if (base + j < N_NODES) row_ptr[base + j] = run;
        run += v[j];
    }
    if (tid == 255) bsum[blockIdx.x] = sdata[255];
}

__global__ __launch_bounds__(256) void k_scan_c2(
        int* __restrict__ row_ptr, const int* __restrict__ bsum,
        int* __restrict__ srcs) {
    __shared__ int pb[64];
    const int t = threadIdx.x;
    if (t < 64) {                       // wave 0: exclusive prefix of bsum
        int v = (t < NCH) ? bsum[t] : 0;
        const int orig = v;
        for (int off = 1; off < 64; off <<= 1) {
            int u = __shfl_up(v, off);
            if (t >= off) v += u;
        }
        pb[t] = v - orig;
    }
    __syncthreads();
    const int i = blockIdx.x * 256 + t;
    if (i < N_NODES) {
        const int rp = row_ptr[i] + pb[i / CHUNK];
        row_ptr[i] = rp;
        srcs[rp] = i;                   // self loop occupies segment slot 0
    } else if (i == N_NODES) row_ptr[N_NODES] = N_TOT;
}

// ---------------------------------------------------------------------------
// Sliced atomic-free scatter over real edges: slice = blockIdx%8 -> one XCD.
// Real edges land at row_ptr[d] + 1 + rank (slot 0 = self loop).
// ---------------------------------------------------------------------------
__global__ __launch_bounds__(256) void k_scatter(
        const int* __restrict__ ei, const int* __restrict__ row_ptr,
        const int* __restrict__ rank, int* __restrict__ srcs) {
    const int slice = blockIdx.x % SLICES;
    const int chunk = blockIdx.x / SLICES;
    const int lo = slice * SL_W;
    const int base = chunk * CH_E;
    const int lim = (base + CH_E < N_EDGES) ? base + CH_E : N_EDGES;
    for (int i = base + threadIdx.x; i < lim; i += 256) {
        const int di = ei[N_EDGES + i];
        if ((uint)(di - lo) < (uint)SL_W)
            srcs[row_ptr[di] + 1 + rank[i]] = ei[i];
    }
}

// ---------------------------------------------------------------------------
// K_agg1 (+ fused node GEMM): 16 lanes/edge (4 groups), uint2 loads,
// unroll x2 -> 8 row-gathers in flight. Epilogue: 2 xor-reduces, elu ->
// x2 row (f32) staged to per-wave LDS -> fused 64x32 GEMM vs W2 (f32,
// coalesced L1-resident column loads) + s2/d2 dots. This replaces the old
// k_node1 kernel, which at 391 blocks (~1.5 waves/SIMD) was pure-latency
// bound (VALUBusy 7.7%, 80 us). Here the ~90-instr tail hides under the
// gather latency of 100K waves.
// ---------------------------------------------------------------------------
__global__ __launch_bounds__(256) void k_agg1(
        const int* __restrict__ row_ptr, const int* __restrict__ srcs,
        const ushort* __restrict__ h1b, const float* __restrict__ s1,
        const float* __restrict__ d1, const float* __restrict__ b1,
        const float* __restrict__ W2, const float* __restrict__ as2,
        const float* __restrict__ ad2,
        ushort* __restrict__ h2b, float* __restrict__ s2,
        float* __restrict__ d2) {
    __shared__ float sx[4][64];                    // per-wave x2 row (f32)
    const int wid = (blockIdx.x * 256 + threadIdx.x) >> 6;
    if (wid >= N_NODES) return;
    const int w = threadIdx.x >> 6;
    const int lane = threadIdx.x & 63;
    const int q = lane >> 4;          // edge group 0..3
    const int c = lane & 15;          // uint2 idx: channels 4c..4c+3
    const int hd = c >> 1;            // head
    const float dh = d1[(size_t)wid * H1 + hd];
    const int beg = row_ptr[wid], end = row_ptr[wid + 1];
    const uint2* hv = (const uint2*)h1b;      // 16 uint2 per node
    float a0 = 0.f, a1 = 0.f, a2 = 0.f, a3 = 0.f, z = 0.f;
    int i = beg + q;
    for (; i + 4 < end; i += 8) {             // edges i, i+4
        const int sA = srcs[i], sB = srcs[i + 4];
        float eA = s1[(size_t)sA * H1 + hd] + dh;
        float eB = s1[(size_t)sB * H1 + hd] + dh;
        eA = eA > 0.f ? eA : SLOPE * eA;
        eB = eB > 0.f ? eB : SLOPE * eB;
        const float xA = __expf(eA), xB = __expf(eB);
        const uint2 UA = hv[(size_t)sA * 16 + c];
        const uint2 UB = hv[(size_t)sB * 16 + c];
        z  += xA + xB;
        a0 += xA * bflo(UA.x) + xB * bflo(UB.x);
        a1 += xA * bfhi(UA.x) + xB * bfhi(UB.x);
        a2 += xA * bflo(UA.y) + xB * bflo(UB.y);
        a3 += xA * bfhi(UA.y) + xB * bfhi(UB.y);
    }
    for (; i < end; i += 4) {
        const int sA = srcs[i];
        float eA = s1[(size_t)sA * H1 + hd] + dh;
        eA = eA > 0.f ? eA : SLOPE * eA;
        const float xA = __expf(eA);
        const uint2 UA = hv[(size_t)sA * 16 + c];
        z  += xA;
        a0 += xA * bflo(UA.x);
        a1 += xA * bfhi(UA.x);
        a2 += xA * bflo(UA.y);
        a3 += xA * bfhi(UA.y);
    }
#pragma unroll
    for (int off = 16; off <= 32; off <<= 1) {
        a0 += __shfl_xor(a0, off); a1 += __shfl_xor(a1, off);
        a2 += __shfl_xor(a2, off); a3 += __shfl_xor(a3, off);
        z  += __shfl_xor(z, off);
    }
    if (lane < 16) {
        const float zi = 1.f / (z + 1e-16f);
        float v0 = a0 * zi + b1[4 * c + 0];
        float v1 = a1 * zi + b1[4 * c + 1];
        float v2 = a2 * zi + b1[4 * c + 2];
        float v3 = a3 * zi + b1[4 * c + 3];
        v0 = v0 > 0.f ? v0 : __expf(v0) - 1.f;     // elu
        v1 = v1 > 0.f ? v1 : __expf(v1) - 1.f;
        v2 = v2 > 0.f ? v2 : __expf(v2) - 1.f;
        v3 = v3 > 0.f ? v3 : __expf(v3) - 1.f;
        *(float4*)&sx[w][4 * lane] = make_float4(v0, v1, v2, v3);
    }
    // In-wave LDS RAW: DS ops execute in order per wave; wave_barrier stops
    // compile-time reordering. No __syncthreads needed (per-wave row).
    __builtin_amdgcn_wave_barrier();

    // fused node GEMM: h2[c] = sum_k x2[k] * W2[k][c]  (lane: kh half, c col)
    const int kh = lane >> 5;          // K half 0..1
    const int oc = lane & 31;          // output channel
    const float4* sxv = (const float4*)&sx[w][kh * 32];   // broadcast reads
    const float* wp0 = W2 + (size_t)(kh * 32) * F2 + oc;  // coalesced 128B/half
    float acc = 0.f;
#pragma unroll
    for (int k4 = 0; k4 < 8; ++k4) {
        const float4 xv = sxv[k4];
        const float* wp = wp0 + (size_t)k4 * 4 * F2;
        acc += xv.x * wp[0]      + xv.y * wp[F2]
             + xv.z * wp[2 * F2] + xv.w * wp[3 * F2];
    }
    acc += __shfl_xor(acc, 32);        // combine K halves; all lanes have h2[oc]

    float sA2 = acc * as2[oc], dA2 = acc * ad2[oc];
#pragma unroll
    for (int off = 1; off <= 16; off <<= 1) {
        sA2 += __shfl_xor(sA2, off);
        dA2 += __shfl_xor(dA2, off);
    }
    if (lane < 32) h2b[(size_t)wid * F2 + oc] = f2bf(acc);
    if (lane == 0) { s2[wid] = sA2; d2[wid] = dA2; }
}

// ---------------------------------------------------------------------------
// K_agg2: 8 lanes/edge (8 groups), uint2 loads, unroll x2 -> 16 gathers in
// flight. Fused log_softmax. Writes d_out directly.
// ---------------------------------------------------------------------------
__global__ __launch_bounds__(256) void k_agg2(
        const int* __restrict__ row_ptr, const int* __restrict__ srcs,
        const ushort* __restrict__ h2b, const float* __restrict__ s2,
        const float* __restrict__ d2, const float* __restrict__ b2,
        float* __restrict__ out) {
    const int wid = (blockIdx.x * 256 + threadIdx.x) >> 6;
    if (wid >= N_NODES) return;
    const int lane = threadIdx.x & 63;
    const int q = lane >> 3;          // edge group 0..7
    const int c = lane & 7;           // uint2 idx: channels 4c..4c+3
    const float dn = d2[wid];
    const int beg = row_ptr[wid], end = row_ptr[wid + 1];
    const uint2* hv = (const uint2*)h2b;      // 8 uint2 per node
    float a0 = 0.f, a1 = 0.f, a2 = 0.f, a3 = 0.f, z = 0.f;
    int i = beg + q;
    for (; i + 8 < end; i += 16) {            // edges i, i+8
        const int sA = srcs[i], sB = srcs[i + 8];
        float eA = s2[sA] + dn;
        float eB = s2[sB] + dn;
        eA = eA > 0.f ? eA : SLOPE * eA;
        eB = eB > 0.f ? eB : SLOPE * eB;
        const float xA = __expf(eA), xB = __expf(eB);
        const uint2 UA = hv[(size_t)sA * 8 + c];
        const uint2 UB = hv[(size_t)sB * 8 + c];
        z  += xA + xB;
        a0 += xA * bflo(UA.x) + xB * bflo(UB.x);
        a1 += xA * bfhi(UA.x) + xB * bfhi(UB.x);
        a2 += xA * bflo(UA.y) + xB * bflo(UB.y);
        a3 += xA * bfhi(UA.y) + xB * bfhi(UB.y);
    }
    for (; i < end; i += 8) {
        const int sA = srcs[i];
        float eA = s2[sA] + dn;
        eA = eA > 0.f ? eA : SLOPE * eA;
        const float xA = __expf(eA);
        const uint2 UA = hv[(size_t)sA * 8 + c];
        z  += xA;
        a0 += xA * bflo(UA.x);
        a1 += xA * bfhi(UA.x);
        a2 += xA * bflo(UA.y);
        a3 += xA * bfhi(UA.y);
    }
#pragma unroll
    for (int off = 8; off <= 32; off <<= 1) {
        a0 += __shfl_xor(a0, off); a1 += __shfl_xor(a1, off);
        a2 += __shfl_xor(a2, off); a3 += __shfl_xor(a3, off);
        z  += __shfl_xor(z, off);
    }
    const float zi = 1.f / (z + 1e-16f);
    const float v0 = a0 * zi + b2[4 * c + 0];
    const float v1 = a1 * zi + b2[4 * c + 1];
    const float v2 = a2 * zi + b2[4 * c + 2];
    const float v3 = a3 * zi + b2[4 * c + 3];
    float m = fmaxf(fmaxf(v0, v1), fmaxf(v2, v3));
#pragma unroll
    for (int off = 1; off <= 4; off <<= 1) m = fmaxf(m, __shfl_xor(m, off));
    float ssum = __expf(v0 - m) + __expf(v1 - m) + __expf(v2 - m) + __expf(v3 - m);
#pragma unroll
    for (int off = 1; off <= 4; off <<= 1) ssum += __shfl_xor(ssum, off);
    const float lse = m + __logf(ssum);
    if (lane < 8)
        ((float4*)out)[(size_t)wid * 8 + c] =
            make_float4(v0 - lse, v1 - lse, v2 - lse, v3 - lse);
}

extern "C" void kernel_launch(void* const* d_in, const int* in_sizes, int n_in,
                              void* d_out, int out_size, void* d_ws, size_t ws_size,
                              hipStream_t stream) {
    const float* x   = (const float*)d_in[0];
    const int*   ei  = (const int*)d_in[1];
    const float* W1  = (const float*)d_in[2];
    const float* as1 = (const float*)d_in[3];
    const float* ad1 = (const float*)d_in[4];
    const float* b1  = (const float*)d_in[5];
    const float* W2  = (const float*)d_in[6];
    const float* as2 = (const float*)d_in[7];
    const float* ad2 = (const float*)d_in[8];
    const float* b2  = (const float*)d_in[9];
    float* out = (float*)d_out;

    // Workspace layout (x2b removed: layer-2 GEMM fused into k_agg1)
    ushort* h1b = (ushort*)d_ws;                   // N*64 bf16
    ushort* h2b = h1b + (size_t)N_NODES * F1;      // N*32 bf16
    float*  s1  = (float*)(h2b + (size_t)N_NODES * F2);  // N*8
    float*  d1  = s1 + (size_t)N_NODES * H1;       // N*8
    float*  s2  = d1 + (size_t)N_NODES * H1;       // N
    float*  d2  = s2 + N_NODES;                    // N
    int* cnt     = (int*)(d2 + N_NODES);           // N
    int* rank    = cnt + N_NODES;                  // N_EDGES
    int* row_ptr = rank + N_EDGES;                 // N+1
    int* bsum    = row_ptr + N_NODES + 1;          // 64
    int* srcs    = bsum + 64;                      // N_TOT

    hipMemsetAsync(cnt, 0, (size_t)N_NODES * sizeof(int), stream);

    const int nb_w = (N_NODES * 64 + 255) / 256;   // one wave per node

    k_gemm1_hist<<<NB_G + NB_H, 256, 0, stream>>>(x, W1, as1, ad1, ei,
                                                  h1b, s1, d1, cnt, rank);
    k_scan_a<<<NCH, 256, 0, stream>>>(cnt, row_ptr, bsum);
    k_scan_c2<<<(N_NODES + 256) / 256, 256, 0, stream>>>(row_ptr, bsum, srcs);
    k_scatter<<<SLICES * NCHUNK, 256, 0, stream>>>(ei, row_ptr, rank, srcs);
    k_agg1<<<nb_w, 256, 0, stream>>>(row_ptr, srcs, h1b, s1, d1, b1,
                                     W2, as2, ad2, h2b, s2, d2);
    k_agg2<<<nb_w, 256, 0, stream>>>(row_ptr, srcs, h2b, s2, d2, b2, out);
}

// Round 2
// 397.744 us; speedup vs baseline: 1.0055x; 1.0055x over previous
//
#include <hip/hip_runtime.h>
#include <hip/hip_bf16.h>

#define N_NODES 100000
#define N_EDGES 1600000
#define N_TOT   (N_EDGES + N_NODES)   // edges + self loops
#define F_IN    256
#define F1      64     // H1*C1
#define H1      8
#define C1      8
#define F2      32
#define SLOPE   0.2f
#define CHUNK   2048
#define NCH     ((N_NODES + CHUNK - 1) / CHUNK)   // 49

#define NB_G    ((N_NODES + 255) / 256)           // 391 gemm blocks
#define NB_H    ((N_EDGES + 255) / 256)           // 6250 hist blocks (real edges only)

#define SLICES  8                                  // one dst-slice per XCD
#define SL_W    ((N_NODES + SLICES - 1) / SLICES)  // 12500 nodes/slice
#define CH_E    16384                              // edges per scatter chunk
#define NCHUNK  ((N_EDGES + CH_E - 1) / CH_E)      // 98

typedef unsigned int  uint;
typedef unsigned short ushort;
typedef __attribute__((ext_vector_type(8))) short bf16x8;
typedef __attribute__((ext_vector_type(4))) float f32x4;

__device__ inline ushort f2bf(float f) {               // RNE float->bf16
    uint u = __float_as_uint(f);
    uint r = u + 0x7fffu + ((u >> 16) & 1u);
    return (ushort)(r >> 16);
}
__device__ inline float bflo(uint u) { return __uint_as_float(u << 16); }
__device__ inline float bfhi(uint u) { return __uint_as_float(u & 0xffff0000u); }
__device__ inline uint pk2bf(float a, float b) {
    __hip_bfloat162 h = __float22bfloat162_rn(make_float2(a, b));
    union { __hip_bfloat162 h; uint u; } cv; cv.h = h;
    return cv.u;
}

// ---------------------------------------------------------------------------
// K1 fused: blocks [0,NB_G) = MFMA gemm (h1 = x@W1 + s1/d1 dots);
// blocks [NB_G, NB_G+NB_H) = hist+rank over REAL edges only (self-loops get
// reserved slot 0 per segment -- no atomic needed for them). Device-scope
// atomic rank is ~20 Gops/s structural; the gemm hides under the atomic
// window.
// ---------------------------------------------------------------------------
__global__ __launch_bounds__(256) void k_gemm1_hist(
        const float* __restrict__ x, const float* __restrict__ W1,
        const float* __restrict__ as1, const float* __restrict__ ad1,
        const int* __restrict__ ei,
        ushort* __restrict__ h1b, float* __restrict__ s1, float* __restrict__ d1,
        int* __restrict__ cnt, int* __restrict__ rank) {
    __shared__ union {
        ushort B[F_IN * F1];        // 32 KB: W1 bf16, idx = ((k>>3)*64+n)*8 + (k&7)
        ushort S[4][64][66];        // 33.8 KB: per-wave h staging (pad 66)
    } sm;
    const int tid = threadIdx.x;

    if (blockIdx.x >= NB_G) {                      // ---- hist + rank part ----
        const int e = (blockIdx.x - NB_G) * 256 + tid;
        if (e < N_EDGES)
            rank[e] = atomicAdd(cnt + ei[N_EDGES + e], 1);
        return;
    }

    // ---- MFMA gemm part ----
    for (int i = 0; i < 64; ++i) {                 // stage + swizzle W1
        const int e = i * 256 + tid;               // e = k*64 + n
        const int k = e >> 6, n = e & 63;
        sm.B[((k >> 3) * 64 + n) * 8 + (k & 7)] = f2bf(W1[e]);
    }
    __syncthreads();

    const int wave = tid >> 6, lane = tid & 63;
    const int q = lane >> 4, ln = lane & 15;
    const int rowbase = blockIdx.x * 256 + wave * 64;

    f32x4 acc[4][4];
#pragma unroll
    for (int mt = 0; mt < 4; ++mt)
#pragma unroll
        for (int nt = 0; nt < 4; ++nt) acc[mt][nt] = (f32x4){0.f, 0.f, 0.f, 0.f};

    int rows[4];
#pragma unroll
    for (int mt = 0; mt < 4; ++mt) {
        const int r = rowbase + mt * 16 + ln;
        rows[mt] = r < N_NODES ? r : N_NODES - 1;
    }

    for (int t = 0; t < 8; ++t) {                  // K-loop: 8 x 32
        bf16x8 bfr[4];
#pragma unroll
        for (int nt = 0; nt < 4; ++nt)
            bfr[nt] = *(const bf16x8*)&sm.B[((t * 4 + q) * 64 + nt * 16 + ln) * 8];
#pragma unroll
        for (int mt = 0; mt < 4; ++mt) {
            const float4* ap = (const float4*)(x + (size_t)rows[mt] * F_IN + t * 32 + q * 8);
            const float4 a0 = ap[0], a1 = ap[1];
            uint4 au = make_uint4(pk2bf(a0.x, a0.y), pk2bf(a0.z, a0.w),
                                  pk2bf(a1.x, a1.y), pk2bf(a1.z, a1.w));
            bf16x8 af = *(bf16x8*)&au;
#pragma unroll
            for (int nt = 0; nt < 4; ++nt)
                acc[mt][nt] = __builtin_amdgcn_mfma_f32_16x16x32_bf16(
                                  af, bfr[nt], acc[mt][nt], 0, 0, 0);
        }
    }
    __syncthreads();

    // stage h (bf16): C/D layout col=lane&15, row=q*4+r
#pragma unroll
    for (int mt = 0; mt < 4; ++mt)
#pragma unroll
        for (int nt = 0; nt < 4; ++nt)
#pragma unroll
            for (int r = 0; r < 4; ++r)
                sm.S[wave][mt * 16 + q * 4 + r][nt * 16 + ln] = f2bf(acc[mt][nt][r]);
    __syncthreads();

    const int node = rowbase + lane;
    if (node >= N_NODES) return;
    const uint* srow = (const uint*)&sm.S[wave][lane][0];
    float sacc[H1], dacc[H1];
#pragma unroll
    for (int h = 0; h < H1; ++h) { sacc[h] = 0.f; dacc[h] = 0.f; }
    uint4* hout = (uint4*)(h1b + (size_t)node * F1);
#pragma unroll
    for (int p4 = 0; p4 < 8; ++p4) {               // p4 == head index
        const uint u0 = srow[p4 * 4 + 0], u1 = srow[p4 * 4 + 1];
        const uint u2 = srow[p4 * 4 + 2], u3 = srow[p4 * 4 + 3];
        hout[p4] = make_uint4(u0, u1, u2, u3);
        const float c[8] = {bflo(u0), bfhi(u0), bflo(u1), bfhi(u1),
                            bflo(u2), bfhi(u2), bflo(u3), bfhi(u3)};
#pragma unroll
        for (int j = 0; j < 8; ++j) {
            sacc[p4] += c[j] * as1[p4 * 8 + j];
            dacc[p4] += c[j] * ad1[p4 * 8 + j];
        }
    }
    float4* s4 = (float4*)(s1 + (size_t)node * H1);
    float4* d4 = (float4*)(d1 + (size_t)node * H1);
    s4[0] = make_float4(sacc[0], sacc[1], sacc[2], sacc[3]);
    s4[1] = make_float4(sacc[4], sacc[5], sacc[6], sacc[7]);
    d4[0] = make_float4(dacc[0], dacc[1], dacc[2], dacc[3]);
    d4[1] = make_float4(dacc[4], dacc[5], dacc[6], dacc[7]);
}

// ---------------------------------------------------------------------------
// Scan: per-chunk scan (a) with +1 per node (reserved self-loop slot), then
// fused chunk-prefix + add + self-loop emit (c2).
// ---------------------------------------------------------------------------
__global__ __launch_bounds__(256) void k_scan_a(
        const int* __restrict__ cnt, int* __restrict__ row_ptr,
        int* __restrict__ bsum) {
    __shared__ int sdata[256];
    const int tid = threadIdx.x;
    const int base = blockIdx.x * CHUNK + tid * 8;
    int v[8];
    int tot = 0;
#pragma unroll
    for (int j = 0; j < 8; ++j) {
        v[j] = (base + j < N_NODES) ? cnt[base + j] + 1 : 0;   // +1 = self loop
        tot += v[j];
    }
    sdata[tid] = tot;
    __syncthreads();
    for (int off = 1; off < 256; off <<= 1) {
        int t = (tid >= off) ? sdata[tid - off] : 0;
        __syncthreads();
        sdata[tid] += t;
        __syncthreads();
    }
    int run = sdata[tid] - tot;
#pragma unroll
    for (int j = 0; j < 8; ++j) {
        if (base + j < N_NODES) row_ptr[base + j] = run;
        run += v[j];
    }
    if (tid == 255) bsum[blockIdx.x] = sdata[255];
}

__global__ __launch_bounds__(256) void k_scan_c2(
        int* __restrict__ row_ptr, const int* __restrict__ bsum,
        int* __restrict__ srcs) {
    __shared__ int pb[64];
    const int t = threadIdx.x;
    if (t < 64) {                       // wave 0: exclusive prefix of bsum
        int v = (t < NCH) ? bsum[t] : 0;
        const int orig = v;
        for (int off = 1; off < 64; off <<= 1) {
            int u = __shfl_up(v, off);
            if (t >= off) v += u;
        }
        pb[t] = v - orig;
    }
    __syncthreads();
    const int i = blockIdx.x * 256 + t;
    if (i < N_NODES) {
        const int rp = row_ptr[i] + pb[i / CHUNK];
        row_ptr[i] = rp;
        srcs[rp] = i;                   // self loop occupies segment slot 0
    } else if (i == N_NODES) row_ptr[N_NODES] = N_TOT;
}

// ---------------------------------------------------------------------------
// Sliced atomic-free scatter over real edges: slice = blockIdx%8 -> one XCD.
// Real edges land at row_ptr[d] + 1 + rank (slot 0 = self loop).
// ---------------------------------------------------------------------------
__global__ __launch_bounds__(256) void k_scatter(
        const int* __restrict__ ei, const int* __restrict__ row_ptr,
        const int* __restrict__ rank, int* __restrict__ srcs) {
    const int slice = blockIdx.x % SLICES;
    const int chunk = blockIdx.x / SLICES;
    const int lo = slice * SL_W;
    const int base = chunk * CH_E;
    const int lim = (base + CH_E < N_EDGES) ? base + CH_E : N_EDGES;
    for (int i = base + threadIdx.x; i < lim; i += 256) {
        const int di = ei[N_EDGES + i];
        if ((uint)(di - lo) < (uint)SL_W)
            srcs[row_ptr[di] + 1 + rank[i]] = ei[i];
    }
}

// ---------------------------------------------------------------------------
// K_agg1 (+ fused node GEMM): 8 lanes/edge (8 groups), lane = head, uint4
// (16B) h1 loads -> attention weight (s1 load, leaky, exp) computed exactly
// ONCE per (edge, head); VMEM instr count halved vs the old 16-lane/uint2
// layout which duplicated exp 2x/head (VALUBusy 60% -> main-loop VALU was
// the bottleneck). Epilogue: 3 xor-reduces, elu -> x2 row (f32) staged to
// per-wave LDS -> fused 64x32 GEMM vs W2 + s2/d2 dots (replaces old
// k_node1 which was latency-bound at 391 blocks).
// ---------------------------------------------------------------------------
__global__ __launch_bounds__(256) void k_agg1(
        const int* __restrict__ row_ptr, const int* __restrict__ srcs,
        const ushort* __restrict__ h1b, const float* __restrict__ s1,
        const float* __restrict__ d1, const float* __restrict__ b1,
        const float* __restrict__ W2, const float* __restrict__ as2,
        const float* __restrict__ ad2,
        ushort* __restrict__ h2b, float* __restrict__ s2,
        float* __restrict__ d2) {
    __shared__ float sx[4][64];                    // per-wave x2 row (f32)
    const int wid = (blockIdx.x * 256 + threadIdx.x) >> 6;
    if (wid >= N_NODES) return;
    const int w = threadIdx.x >> 6;
    const int lane = threadIdx.x & 63;
    const int q = lane >> 3;          // edge group 0..7
    const int c = lane & 7;           // head (= uint4 idx: channels 8c..8c+7)
    const float dh = d1[(size_t)wid * H1 + c];
    const int beg = row_ptr[wid], end = row_ptr[wid + 1];
    const uint4* hv = (const uint4*)h1b;      // 8 uint4 per node
    float a0 = 0.f, a1 = 0.f, a2 = 0.f, a3 = 0.f;
    float a4 = 0.f, a5 = 0.f, a6 = 0.f, a7 = 0.f, z = 0.f;
    int i = beg + q;
    for (; i + 8 < end; i += 16) {            // edges i, i+8
        const int sA = srcs[i], sB = srcs[i + 8];
        float eA = s1[(size_t)sA * H1 + c] + dh;
        float eB = s1[(size_t)sB * H1 + c] + dh;
        eA = eA > 0.f ? eA : SLOPE * eA;
        eB = eB > 0.f ? eB : SLOPE * eB;
        const float xA = __expf(eA), xB = __expf(eB);
        const uint4 UA = hv[(size_t)sA * 8 + c];
        const uint4 UB = hv[(size_t)sB * 8 + c];
        z  += xA + xB;
        a0 += xA * bflo(UA.x) + xB * bflo(UB.x);
        a1 += xA * bfhi(UA.x) + xB * bfhi(UB.x);
        a2 += xA * bflo(UA.y) + xB * bflo(UB.y);
        a3 += xA * bfhi(UA.y) + xB * bfhi(UB.y);
        a4 += xA * bflo(UA.z) + xB * bflo(UB.z);
        a5 += xA * bfhi(UA.z) + xB * bfhi(UB.z);
        a6 += xA * bflo(UA.w) + xB * bflo(UB.w);
        a7 += xA * bfhi(UA.w) + xB * bfhi(UB.w);
    }
    for (; i < end; i += 8) {
        const int sA = srcs[i];
        float eA = s1[(size_t)sA * H1 + c] + dh;
        eA = eA > 0.f ? eA : SLOPE * eA;
        const float xA = __expf(eA);
        const uint4 UA = hv[(size_t)sA * 8 + c];
        z  += xA;
        a0 += xA * bflo(UA.x);
        a1 += xA * bfhi(UA.x);
        a2 += xA * bflo(UA.y);
        a3 += xA * bfhi(UA.y);
        a4 += xA * bflo(UA.z);
        a5 += xA * bfhi(UA.z);
        a6 += xA * bflo(UA.w);
        a7 += xA * bfhi(UA.w);
    }
#pragma unroll
    for (int off = 8; off <= 32; off <<= 1) {
        a0 += __shfl_xor(a0, off); a1 += __shfl_xor(a1, off);
        a2 += __shfl_xor(a2, off); a3 += __shfl_xor(a3, off);
        a4 += __shfl_xor(a4, off); a5 += __shfl_xor(a5, off);
        a6 += __shfl_xor(a6, off); a7 += __shfl_xor(a7, off);
        z  += __shfl_xor(z, off);
    }
    if (lane < 8) {
        const float zi = 1.f / (z + 1e-16f);
        float v0 = a0 * zi + b1[c * 8 + 0];
        float v1 = a1 * zi + b1[c * 8 + 1];
        float v2 = a2 * zi + b1[c * 8 + 2];
        float v3 = a3 * zi + b1[c * 8 + 3];
        float v4 = a4 * zi + b1[c * 8 + 4];
        float v5 = a5 * zi + b1[c * 8 + 5];
        float v6 = a6 * zi + b1[c * 8 + 6];
        float v7 = a7 * zi + b1[c * 8 + 7];
        v0 = v0 > 0.f ? v0 : __expf(v0) - 1.f;     // elu
        v1 = v1 > 0.f ? v1 : __expf(v1) - 1.f;
        v2 = v2 > 0.f ? v2 : __expf(v2) - 1.f;
        v3 = v3 > 0.f ? v3 : __expf(v3) - 1.f;
        v4 = v4 > 0.f ? v4 : __expf(v4) - 1.f;
        v5 = v5 > 0.f ? v5 : __expf(v5) - 1.f;
        v6 = v6 > 0.f ? v6 : __expf(v6) - 1.f;
        v7 = v7 > 0.f ? v7 : __expf(v7) - 1.f;
        *(float4*)&sx[w][c * 8 + 0] = make_float4(v0, v1, v2, v3);
        *(float4*)&sx[w][c * 8 + 4] = make_float4(v4, v5, v6, v7);
    }
    // In-wave LDS RAW: DS ops execute in order per wave; wave_barrier stops
    // compile-time reordering. No __syncthreads needed (per-wave row).
    __builtin_amdgcn_wave_barrier();

    // fused node GEMM: h2[c] = sum_k x2[k] * W2[k][c]  (lane: kh half, c col)
    const int kh = lane >> 5;          // K half 0..1
    const int oc = lane & 31;          // output channel
    const float4* sxv = (const float4*)&sx[w][kh * 32];   // broadcast reads
    const float* wp0 = W2 + (size_t)(kh * 32) * F2 + oc;  // coalesced 128B/half
    float acc = 0.f;
#pragma unroll
    for (int k4 = 0; k4 < 8; ++k4) {
        const float4 xv = sxv[k4];
        const float* wp = wp0 + (size_t)k4 * 4 * F2;
        acc += xv.x * wp[0]      + xv.y * wp[F2]
             + xv.z * wp[2 * F2] + xv.w * wp[3 * F2];
    }
    acc += __shfl_xor(acc, 32);        // combine K halves; all lanes have h2[oc]

    float sA2 = acc * as2[oc], dA2 = acc * ad2[oc];
#pragma unroll
    for (int off = 1; off <= 16; off <<= 1) {
        sA2 += __shfl_xor(sA2, off);
        dA2 += __shfl_xor(dA2, off);
    }
    if (lane < 32) h2b[(size_t)wid * F2 + oc] = f2bf(acc);
    if (lane == 0) { s2[wid] = sA2; d2[wid] = dA2; }
}

// ---------------------------------------------------------------------------
// K_agg2: 4 lanes/edge (16 groups), uint4 loads, unroll x2 -> 32 gathers in
// flight; exp redundancy 4x (was 8x). Fused log_softmax. Writes d_out.
// ---------------------------------------------------------------------------
__global__ __launch_bounds__(256) void k_agg2(
        const int* __restrict__ row_ptr, const int* __restrict__ srcs,
        const ushort* __restrict__ h2b, const float* __restrict__ s2,
        const float* __restrict__ d2, const float* __restrict__ b2,
        float* __restrict__ out) {
    const int wid = (blockIdx.x * 256 + threadIdx.x) >> 6;
    if (wid >= N_NODES) return;
    const int lane = threadIdx.x & 63;
    const int q = lane >> 2;          // edge group 0..15
    const int c = lane & 3;           // uint4 idx: channels 8c..8c+7
    const float dn = d2[wid];
    const int beg = row_ptr[wid], end = row_ptr[wid + 1];
    const uint4* hv = (const uint4*)h2b;      // 4 uint4 per node
    float a0 = 0.f, a1 = 0.f, a2 = 0.f, a3 = 0.f;
    float a4 = 0.f, a5 = 0.f, a6 = 0.f, a7 = 0.f, z = 0.f;
    int i = beg + q;
    for (; i + 16 < end; i += 32) {           // edges i, i+16
        const int sA = srcs[i], sB = srcs[i + 16];
        float eA = s2[sA] + dn;
        float eB = s2[sB] + dn;
        eA = eA > 0.f ? eA : SLOPE * eA;
        eB = eB > 0.f ? eB : SLOPE * eB;
        const float xA = __expf(eA), xB = __expf(eB);
        const uint4 UA = hv[(size_t)sA * 4 + c];
        const uint4 UB = hv[(size_t)sB * 4 + c];
        z  += xA + xB;
        a0 += xA * bflo(UA.x) + xB * bflo(UB.x);
        a1 += xA * bfhi(UA.x) + xB * bfhi(UB.x);
        a2 += xA * bflo(UA.y) + xB * bflo(UB.y);
        a3 += xA * bfhi(UA.y) + xB * bfhi(UB.y);
        a4 += xA * bflo(UA.z) + xB * bflo(UB.z);
        a5 += xA * bfhi(UA.z) + xB * bfhi(UB.z);
        a6 += xA * bflo(UA.w) + xB * bflo(UB.w);
        a7 += xA * bfhi(UA.w) + xB * bfhi(UB.w);
    }
    for (; i < end; i += 16) {
        const int sA = srcs[i];
        float eA = s2[sA] + dn;
        eA = eA > 0.f ? eA : SLOPE * eA;
        const float xA = __expf(eA);
        const uint4 UA = hv[(size_t)sA * 4 + c];
        z  += xA;
        a0 += xA * bflo(UA.x);
        a1 += xA * bfhi(UA.x);
        a2 += xA * bflo(UA.y);
        a3 += xA * bfhi(UA.y);
        a4 += xA * bflo(UA.z);
        a5 += xA * bfhi(UA.z);
        a6 += xA * bflo(UA.w);
        a7 += xA * bfhi(UA.w);
    }
#pragma unroll
    for (int off = 4; off <= 32; off <<= 1) {
        a0 += __shfl_xor(a0, off); a1 += __shfl_xor(a1, off);
        a2 += __shfl_xor(a2, off); a3 += __shfl_xor(a3, off);
        a4 += __shfl_xor(a4, off); a5 += __shfl_xor(a5, off);
        a6 += __shfl_xor(a6, off); a7 += __shfl_xor(a7, off);
        z  += __shfl_xor(z, off);
    }
    const float zi = 1.f / (z + 1e-16f);
    const float v0 = a0 * zi + b2[8 * c + 0];
    const float v1 = a1 * zi + b2[8 * c + 1];
    const float v2 = a2 * zi + b2[8 * c + 2];
    const float v3 = a3 * zi + b2[8 * c + 3];
    const float v4 = a4 * zi + b2[8 * c + 4];
    const float v5 = a5 * zi + b2[8 * c + 5];
    const float v6 = a6 * zi + b2[8 * c + 6];
    const float v7 = a7 * zi + b2[8 * c + 7];
    float m = fmaxf(fmaxf(fmaxf(v0, v1), fmaxf(v2, v3)),
                    fmaxf(fmaxf(v4, v5), fmaxf(v6, v7)));
#pragma unroll
    for (int off = 1; off <= 2; off <<= 1) m = fmaxf(m, __shfl_xor(m, off));
    float ssum = __expf(v0 - m) + __expf(v1 - m) + __expf(v2 - m) + __expf(v3 - m)
               + __expf(v4 - m) + __expf(v5 - m) + __expf(v6 - m) + __expf(v7 - m);
#pragma unroll
    for (int off = 1; off <= 2; off <<= 1) ssum += __shfl_xor(ssum, off);
    const float lse = m + __logf(ssum);
    if (lane < 4) {
        float4* o4 = (float4*)out;
        o4[(size_t)wid * 8 + 2 * c + 0] =
            make_float4(v0 - lse, v1 - lse, v2 - lse, v3 - lse);
        o4[(size_t)wid * 8 + 2 * c + 1] =
            make_float4(v4 - lse, v5 - lse, v6 - lse, v7 - lse);
    }
}

extern "C" void kernel_launch(void* const* d_in, const int* in_sizes, int n_in,
                              void* d_out, int out_size, void* d_ws, size_t ws_size,
                              hipStream_t stream) {
    const float* x   = (const float*)d_in[0];
    const int*   ei  = (const int*)d_in[1];
    const float* W1  = (const float*)d_in[2];
    const float* as1 = (const float*)d_in[3];
    const float* ad1 = (const float*)d_in[4];
    const float* b1  = (const float*)d_in[5];
    const float* W2  = (const float*)d_in[6];
    const float* as2 = (const float*)d_in[7];
    const float* ad2 = (const float*)d_in[8];
    const float* b2  = (const float*)d_in[9];
    float* out = (float*)d_out;

    // Workspace layout (x2b removed: layer-2 GEMM fused into k_agg1)
    ushort* h1b = (ushort*)d_ws;                   // N*64 bf16
    ushort* h2b = h1b + (size_t)N_NODES * F1;      // N*32 bf16
    float*  s1  = (float*)(h2b + (size_t)N_NODES * F2);  // N*8
    float*  d1  = s1 + (size_t)N_NODES * H1;       // N*8
    float*  s2  = d1 + (size_t)N_NODES * H1;       // N
    float*  d2  = s2 + N_NODES;                    // N
    int* cnt     = (int*)(d2 + N_NODES);           // N
    int* rank    = cnt + N_NODES;                  // N_EDGES
    int* row_ptr = rank + N_EDGES;                 // N+1
    int* bsum    = row_ptr + N_NODES + 1;          // 64
    int* srcs    = bsum + 64;                      // N_TOT

    hipMemsetAsync(cnt, 0, (size_t)N_NODES * sizeof(int), stream);

    const int nb_w = (N_NODES * 64 + 255) / 256;   // one wave per node

    k_gemm1_hist<<<NB_G + NB_H, 256, 0, stream>>>(x, W1, as1, ad1, ei,
                                                  h1b, s1, d1, cnt, rank);
    k_scan_a<<<NCH, 256, 0, stream>>>(cnt, row_ptr, bsum);
    k_scan_c2<<<(N_NODES + 256) / 256, 256, 0, stream>>>(row_ptr, bsum, srcs);
    k_scatter<<<SLICES * NCHUNK, 256, 0, stream>>>(ei, row_ptr, rank, srcs);
    k_agg1<<<nb_w, 256, 0, stream>>>(row_ptr, srcs, h1b, s1, d1, b1,
                                     W2, as2, ad2, h2b, s2, d2);
    k_agg2<<<nb_w, 256, 0, stream>>>(row_ptr, srcs, h2b, s2, d2, b2, out);
}

// Round 3
// 368.827 us; speedup vs baseline: 1.0844x; 1.0784x over previous
//
#include <hip/hip_runtime.h>
#include <hip/hip_bf16.h>

#define N_NODES 100000
#define N_EDGES 1600000
#define N_TOT   (N_EDGES + N_NODES)   // edges + self loops
#define F_IN    256
#define F1      64     // H1*C1
#define H1      8
#define C1      8
#define F2      32
#define SLOPE   0.2f
#define CHUNK   2048
#define NCH     ((N_NODES + CHUNK - 1) / CHUNK)   // 49

#define NB_G    ((N_NODES + 255) / 256)           // 391 gemm blocks

// counting-sort CSR build (no global atomics)
#define EB      4096                               // edges per P1/P3 block
#define NB1     ((N_EDGES + EB - 1) / EB)          // 391
#define BW      256                                // nodes per bucket
#define NBKT    ((N_NODES + BW - 1) / BW)          // 391

typedef unsigned int  uint;
typedef unsigned short ushort;
typedef __attribute__((ext_vector_type(8))) short bf16x8;
typedef __attribute__((ext_vector_type(4))) float f32x4;

__device__ inline ushort f2bf(float f) {               // RNE float->bf16
    uint u = __float_as_uint(f);
    uint r = u + 0x7fffu + ((u >> 16) & 1u);
    return (ushort)(r >> 16);
}
__device__ inline float bflo(uint u) { return __uint_as_float(u << 16); }
__device__ inline float bfhi(uint u) { return __uint_as_float(u & 0xffff0000u); }
__device__ inline uint pk2bf(float a, float b) {
    __hip_bfloat162 h = __float22bfloat162_rn(make_float2(a, b));
    union { __hip_bfloat162 h; uint u; } cv; cv.h = h;
    return cv.u;
}

// Block-wide exclusive scan of colsum[NBKT] -> sb[0..NBKT] (sb[NBKT]=total).
// 256 threads; thread t owns elements 2t, 2t+1. sc = 256-int scratch.
__device__ inline void bucket_bases(const int* __restrict__ colsum,
                                    int* sc, int* sb, int tid) {
    const int i0 = 2 * tid, i1 = 2 * tid + 1;
    const int a0 = (i0 < NBKT) ? colsum[i0] : 0;
    const int a1 = (i1 < NBKT) ? colsum[i1] : 0;
    sc[tid] = a0 + a1;
    __syncthreads();
    for (int off = 1; off < 256; off <<= 1) {
        int t = (tid >= off) ? sc[tid - off] : 0;
        __syncthreads();
        sc[tid] += t;
        __syncthreads();
    }
    const int excl = sc[tid] - (a0 + a1);
    if (i0 < NBKT)  sb[i0] = excl;
    if (i1 <= NBKT) sb[i1] = excl + a0;       // writes sb[NBKT] (=total) too
    __syncthreads();
}

// ---------------------------------------------------------------------------
// K1 fused: blocks [0,NB_G) = MFMA gemm (h1 = x@W1 + s1/d1 dots);
// blocks [NB_G, NB_G+NB1) = P1 bucket-count over real edges (LDS histogram
// of 391 coarse buckets, plain stores to bcnt matrix -- NO global atomics;
// the old device-scope atomic rank was a structural ~20 Gops/s / ~85us
// window).
// ---------------------------------------------------------------------------
__global__ __launch_bounds__(256) void k_gemm1_p1(
        const float* __restrict__ x, const float* __restrict__ W1,
        const float* __restrict__ as1, const float* __restrict__ ad1,
        const int* __restrict__ ei,
        ushort* __restrict__ h1b, float* __restrict__ s1, float* __restrict__ d1,
        int* __restrict__ bcnt) {
    __shared__ union {
        ushort B[F_IN * F1];        // 32 KB: W1 bf16, idx = ((k>>3)*64+n)*8 + (k&7)
        ushort S[4][64][66];        // 33.8 KB: per-wave h staging (pad 66)
        int    H[NBKT];             // P1 histogram
    } sm;
    const int tid = threadIdx.x;

    if (blockIdx.x >= NB_G) {                      // ---- P1 bucket count ----
        const int blk = blockIdx.x - NB_G;
        for (int j = tid; j < NBKT; j += 256) sm.H[j] = 0;
        __syncthreads();
        const int e0 = blk * EB;
        const int lim = (e0 + EB < N_EDGES) ? e0 + EB : N_EDGES;
        for (int i = e0 + tid; i < lim; i += 256)
            atomicAdd(&sm.H[ei[N_EDGES + i] >> 8], 1);   // LDS atomic
        __syncthreads();
        for (int j = tid; j < NBKT; j += 256)
            bcnt[j * NB1 + blk] = sm.H[j];
        return;
    }

    // ---- MFMA gemm part ----
    for (int i = 0; i < 64; ++i) {                 // stage + swizzle W1
        const int e = i * 256 + tid;               // e = k*64 + n
        const int k = e >> 6, n = e & 63;
        sm.B[((k >> 3) * 64 + n) * 8 + (k & 7)] = f2bf(W1[e]);
    }
    __syncthreads();

    const int wave = tid >> 6, lane = tid & 63;
    const int q = lane >> 4, ln = lane & 15;
    const int rowbase = blockIdx.x * 256 + wave * 64;

    f32x4 acc[4][4];
#pragma unroll
    for (int mt = 0; mt < 4; ++mt)
#pragma unroll
        for (int nt = 0; nt < 4; ++nt) acc[mt][nt] = (f32x4){0.f, 0.f, 0.f, 0.f};

    int rows[4];
#pragma unroll
    for (int mt = 0; mt < 4; ++mt) {
        const int r = rowbase + mt * 16 + ln;
        rows[mt] = r < N_NODES ? r : N_NODES - 1;
    }

    for (int t = 0; t < 8; ++t) {                  // K-loop: 8 x 32
        bf16x8 bfr[4];
#pragma unroll
        for (int nt = 0; nt < 4; ++nt)
            bfr[nt] = *(const bf16x8*)&sm.B[((t * 4 + q) * 64 + nt * 16 + ln) * 8];
#pragma unroll
        for (int mt = 0; mt < 4; ++mt) {
            const float4* ap = (const float4*)(x + (size_t)rows[mt] * F_IN + t * 32 + q * 8);
            const float4 a0 = ap[0], a1 = ap[1];
            uint4 au = make_uint4(pk2bf(a0.x, a0.y), pk2bf(a0.z, a0.w),
                                  pk2bf(a1.x, a1.y), pk2bf(a1.z, a1.w));
            bf16x8 af = *(bf16x8*)&au;
#pragma unroll
            for (int nt = 0; nt < 4; ++nt)
                acc[mt][nt] = __builtin_amdgcn_mfma_f32_16x16x32_bf16(
                                  af, bfr[nt], acc[mt][nt], 0, 0, 0);
        }
    }
    __syncthreads();

    // stage h (bf16): C/D layout col=lane&15, row=q*4+r
#pragma unroll
    for (int mt = 0; mt < 4; ++mt)
#pragma unroll
        for (int nt = 0; nt < 4; ++nt)
#pragma unroll
            for (int r = 0; r < 4; ++r)
                sm.S[wave][mt * 16 + q * 4 + r][nt * 16 + ln] = f2bf(acc[mt][nt][r]);
    __syncthreads();

    const int node = rowbase + lane;
    if (node >= N_NODES) return;
    const uint* srow = (const uint*)&sm.S[wave][lane][0];
    float sacc[H1], dacc[H1];
#pragma unroll
    for (int h = 0; h < H1; ++h) { sacc[h] = 0.f; dacc[h] = 0.f; }
    uint4* hout = (uint4*)(h1b + (size_t)node * F1);
#pragma unroll
    for (int p4 = 0; p4 < 8; ++p4) {               // p4 == head index
        const uint u0 = srow[p4 * 4 + 0], u1 = srow[p4 * 4 + 1];
        const uint u2 = srow[p4 * 4 + 2], u3 = srow[p4 * 4 + 3];
        hout[p4] = make_uint4(u0, u1, u2, u3);
        const float c[8] = {bflo(u0), bfhi(u0), bflo(u1), bfhi(u1),
                            bflo(u2), bfhi(u2), bflo(u3), bfhi(u3)};
#pragma unroll
        for (int j = 0; j < 8; ++j) {
            sacc[p4] += c[j] * as1[p4 * 8 + j];
            dacc[p4] += c[j] * ad1[p4 * 8 + j];
        }
    }
    float4* s4 = (float4*)(s1 + (size_t)node * H1);
    float4* d4 = (float4*)(d1 + (size_t)node * H1);
    s4[0] = make_float4(sacc[0], sacc[1], sacc[2], sacc[3]);
    s4[1] = make_float4(sacc[4], sacc[5], sacc[6], sacc[7]);
    d4[0] = make_float4(dacc[0], dacc[1], dacc[2], dacc[3]);
    d4[1] = make_float4(dacc[4], dacc[5], dacc[6], dacc[7]);
}

// ---------------------------------------------------------------------------
// P2: per-bucket exclusive scan of bcnt[bucket][*] across blocks (in place)
// + column sums. One wave per bucket.
// ---------------------------------------------------------------------------
__global__ __launch_bounds__(64) void k_p2(
        int* __restrict__ bcnt, int* __restrict__ colsum) {
    const int col = blockIdx.x, lane = threadIdx.x;
    int carry = 0;
    for (int c0 = 0; c0 < NB1; c0 += 64) {
        const int idx = c0 + lane;
        const int v = (idx < NB1) ? bcnt[col * NB1 + idx] : 0;
        int s = v;
#pragma unroll
        for (int off = 1; off < 64; off <<= 1) {
            int u = __shfl_up(s, off);
            if (lane >= off) s += u;
        }
        if (idx < NB1) bcnt[col * NB1 + idx] = carry + s - v;
        carry += __shfl(s, 63);
    }
    if (lane == 0) colsum[col] = carry;
}

// ---------------------------------------------------------------------------
// P3: bucket scatter. Each block re-reads its EB edges, places (src,dst)
// into bucket-ordered tmp via LDS cursors = base[bucket] + myBlockOffset.
// ---------------------------------------------------------------------------
__global__ __launch_bounds__(256) void k_p3(
        const int* __restrict__ ei, const int* __restrict__ bcnt,
        const int* __restrict__ colsum, int2* __restrict__ tmp) {
    __shared__ int sc[256];
    __shared__ int cur[NBKT + 1];
    const int tid = threadIdx.x, blk = blockIdx.x;
    bucket_bases(colsum, sc, cur, tid);
    for (int b = tid; b < NBKT; b += 256) cur[b] += bcnt[b * NB1 + blk];
    __syncthreads();
    const int e0 = blk * EB;
    const int lim = (e0 + EB < N_EDGES) ? e0 + EB : N_EDGES;
    for (int i = e0 + tid; i < lim; i += 256) {
        const int s = ei[i], d = ei[N_EDGES + i];
        const int pos = atomicAdd(&cur[d >> 8], 1);     // LDS atomic
        tmp[pos] = make_int2(s, d);
    }
}

// ---------------------------------------------------------------------------
// P4: per-node counts. One block per bucket (256 nodes); LDS histogram over
// the bucket's tmp range; plain stores to cnt (no memset needed).
// ---------------------------------------------------------------------------
__global__ __launch_bounds__(256) void k_p4(
        const int2* __restrict__ tmp, const int* __restrict__ colsum,
        int* __restrict__ cnt) {
    __shared__ int sc[256];
    __shared__ int sb[NBKT + 1];
    __shared__ int h[BW];
    const int tid = threadIdx.x, b = blockIdx.x;
    bucket_bases(colsum, sc, sb, tid);
    h[tid] = 0;
    __syncthreads();
    const int lo = sb[b], hi = sb[b + 1];
    for (int i = lo + tid; i < hi; i += 256)
        atomicAdd(&h[tmp[i].y & (BW - 1)], 1);          // LDS atomic
    __syncthreads();
    const int n = b * BW + tid;
    if (n < N_NODES) cnt[n] = h[tid];
}

// ---------------------------------------------------------------------------
// Scan: per-chunk scan (a) with +1 per node (reserved self-loop slot), then
// fused chunk-prefix + add + self-loop emit (c2).
// ---------------------------------------------------------------------------
__global__ __launch_bounds__(256) void k_scan_a(
        const int* __restrict__ cnt, int* __restrict__ row_ptr,
        int* __restrict__ bsum) {
    __shared__ int sdata[256];
    const int tid = threadIdx.x;
    const int base = blockIdx.x * CHUNK + tid * 8;
    int v[8];
    int tot = 0;
#pragma unroll
    for (int j = 0; j < 8; ++j) {
        v[j] = (base + j < N_NODES) ? cnt[base + j] + 1 : 0;   // +1 = self loop
        tot += v[j];
    }
    sdata[tid] = tot;
    __syncthreads();
    for (int off = 1; off < 256; off <<= 1) {
        int t = (tid >= off) ? sdata[tid - off] : 0;
        __syncthreads();
        sdata[tid] += t;
        __syncthreads();
    }
    int run = sdata[tid] - tot;
#pragma unroll
    for (int j = 0; j < 8; ++j) {
        if (base + j < N_NODES) row_ptr[base + j] = run;
        run += v[j];
    }
    if (tid == 255) bsum[blockIdx.x] = sdata[255];
}

__global__ __launch_bounds__(256) void k_scan_c2(
        int* __restrict__ row_ptr, const int* __restrict__ bsum,
        int* __restrict__ srcs) {
    __shared__ int pb[64];
    const int t = threadIdx.x;
    if (t < 64) {                       // wave 0: exclusive prefix of bsum
        int v = (t < NCH) ? bsum[t] : 0;
        const int orig = v;
        for (int off = 1; off < 64; off <<= 1) {
            int u = __shfl_up(v, off);
            if (t >= off) v += u;
        }
        pb[t] = v - orig;
    }
    __syncthreads();
    const int i = blockIdx.x * 256 + t;
    if (i < N_NODES) {
        const int rp = row_ptr[i] + pb[i / CHUNK];
        row_ptr[i] = rp;
        srcs[rp] = i;                   // self loop occupies segment slot 0
    } else if (i == N_NODES) row_ptr[N_NODES] = N_TOT;
}

// ---------------------------------------------------------------------------
// P6: final placement. One block per bucket: LDS row_ptr + per-node cursors;
// real edges land at row_ptr[d] + 1 + rank (slot 0 = self loop). Replaces
// the old k_scatter (which needed the atomic-derived rank array).
// ---------------------------------------------------------------------------
__global__ __launch_bounds__(256) void k_p6(
        const int2* __restrict__ tmp, const int* __restrict__ colsum,
        const int* __restrict__ row_ptr, int* __restrict__ srcs) {
    __shared__ int sc[256];
    __shared__ int sb[NBKT + 1];
    __shared__ int rp[BW];
    __shared__ int cur[BW];
    const int tid = threadIdx.x, b = blockIdx.x;
    bucket_bases(colsum, sc, sb, tid);
    const int n = b * BW + tid;
    rp[tid] = (n < N_NODES) ? row_ptr[n] : 0;
    cur[tid] = 0;
    __syncthreads();
    const int lo = sb[b], hi = sb[b + 1];
    for (int i = lo + tid; i < hi; i += 256) {
        const int2 e = tmp[i];
        const int loc = e.y & (BW - 1);
        const int r = atomicAdd(&cur[loc], 1);          // LDS atomic
        srcs[rp[loc] + 1 + r] = e.x;
    }
}

// ---------------------------------------------------------------------------
// K_agg1 (+ fused node GEMM): 8 lanes/edge, lane = head, uint4 h1 loads;
// attention weight computed once per (edge, head). Epilogue: xor-reduces,
// elu -> x2 row to per-wave LDS -> fused 64x32 GEMM vs W2 + s2/d2 dots.
// ---------------------------------------------------------------------------
__global__ __launch_bounds__(256) void k_agg1(
        const int* __restrict__ row_ptr, const int* __restrict__ srcs,
        const ushort* __restrict__ h1b, const float* __restrict__ s1,
        const float* __restrict__ d1, const float* __restrict__ b1,
        const float* __restrict__ W2, const float* __restrict__ as2,
        const float* __restrict__ ad2,
        ushort* __restrict__ h2b, float* __restrict__ s2,
        float* __restrict__ d2) {
    __shared__ float sx[4][64];                    // per-wave x2 row (f32)
    const int wid = (blockIdx.x * 256 + threadIdx.x) >> 6;
    if (wid >= N_NODES) return;
    const int w = threadIdx.x >> 6;
    const int lane = threadIdx.x & 63;
    const int q = lane >> 3;          // edge group 0..7
    const int c = lane & 7;           // head (= uint4 idx: channels 8c..8c+7)
    const float dh = d1[(size_t)wid * H1 + c];
    const int beg = row_ptr[wid], end = row_ptr[wid + 1];
    const uint4* hv = (const uint4*)h1b;      // 8 uint4 per node
    float a0 = 0.f, a1 = 0.f, a2 = 0.f, a3 = 0.f;
    float a4 = 0.f, a5 = 0.f, a6 = 0.f, a7 = 0.f, z = 0.f;
    int i = beg + q;
    for (; i + 8 < end; i += 16) {            // edges i, i+8
        const int sA = srcs[i], sB = srcs[i + 8];
        float eA = s1[(size_t)sA * H1 + c] + dh;
        float eB = s1[(size_t)sB * H1 + c] + dh;
        eA = eA > 0.f ? eA : SLOPE * eA;
        eB = eB > 0.f ? eB : SLOPE * eB;
        const float xA = __expf(eA), xB = __expf(eB);
        const uint4 UA = hv[(size_t)sA * 8 + c];
        const uint4 UB = hv[(size_t)sB * 8 + c];
        z  += xA + xB;
        a0 += xA * bflo(UA.x) + xB * bflo(UB.x);
        a1 += xA * bfhi(UA.x) + xB * bfhi(UB.x);
        a2 += xA * bflo(UA.y) + xB * bflo(UB.y);
        a3 += xA * bfhi(UA.y) + xB * bfhi(UB.y);
        a4 += xA * bflo(UA.z) + xB * bflo(UB.z);
        a5 += xA * bfhi(UA.z) + xB * bfhi(UB.z);
        a6 += xA * bflo(UA.w) + xB * bflo(UB.w);
        a7 += xA * bfhi(UA.w) + xB * bfhi(UB.w);
    }
    for (; i < end; i += 8) {
        const int sA = srcs[i];
        float eA = s1[(size_t)sA * H1 + c] + dh;
        eA = eA > 0.f ? eA : SLOPE * eA;
        const float xA = __expf(eA);
        const uint4 UA = hv[(size_t)sA * 8 + c];
        z  += xA;
        a0 += xA * bflo(UA.x);
        a1 += xA * bfhi(UA.x);
        a2 += xA * bflo(UA.y);
        a3 += xA * bfhi(UA.y);
        a4 += xA * bflo(UA.z);
        a5 += xA * bfhi(UA.z);
        a6 += xA * bflo(UA.w);
        a7 += xA * bfhi(UA.w);
    }
#pragma unroll
    for (int off = 8; off <= 32; off <<= 1) {
        a0 += __shfl_xor(a0, off); a1 += __shfl_xor(a1, off);
        a2 += __shfl_xor(a2, off); a3 += __shfl_xor(a3, off);
        a4 += __shfl_xor(a4, off); a5 += __shfl_xor(a5, off);
        a6 += __shfl_xor(a6, off); a7 += __shfl_xor(a7, off);
        z  += __shfl_xor(z, off);
    }
    if (lane < 8) {
        const float zi = 1.f / (z + 1e-16f);
        float v0 = a0 * zi + b1[c * 8 + 0];
        float v1 = a1 * zi + b1[c * 8 + 1];
        float v2 = a2 * zi + b1[c * 8 + 2];
        float v3 = a3 * zi + b1[c * 8 + 3];
        float v4 = a4 * zi + b1[c * 8 + 4];
        float v5 = a5 * zi + b1[c * 8 + 5];
        float v6 = a6 * zi + b1[c * 8 + 6];
        float v7 = a7 * zi + b1[c * 8 + 7];
        v0 = v0 > 0.f ? v0 : __expf(v0) - 1.f;     // elu
        v1 = v1 > 0.f ? v1 : __expf(v1) - 1.f;
        v2 = v2 > 0.f ? v2 : __expf(v2) - 1.f;
        v3 = v3 > 0.f ? v3 : __expf(v3) - 1.f;
        v4 = v4 > 0.f ? v4 : __expf(v4) - 1.f;
        v5 = v5 > 0.f ? v5 : __expf(v5) - 1.f;
        v6 = v6 > 0.f ? v6 : __expf(v6) - 1.f;
        v7 = v7 > 0.f ? v7 : __expf(v7) - 1.f;
        *(float4*)&sx[w][c * 8 + 0] = make_float4(v0, v1, v2, v3);
        *(float4*)&sx[w][c * 8 + 4] = make_float4(v4, v5, v6, v7);
    }
    // In-wave LDS RAW: DS ops execute in order per wave; wave_barrier stops
    // compile-time reordering. No __syncthreads needed (per-wave row).
    __builtin_amdgcn_wave_barrier();

    // fused node GEMM: h2[c] = sum_k x2[k] * W2[k][c]  (lane: kh half, c col)
    const int kh = lane >> 5;          // K half 0..1
    const int oc = lane & 31;          // output channel
    const float4* sxv = (const float4*)&sx[w][kh * 32];   // broadcast reads
    const float* wp0 = W2 + (size_t)(kh * 32) * F2 + oc;  // coalesced 128B/half
    float acc = 0.f;
#pragma unroll
    for (int k4 = 0; k4 < 8; ++k4) {
        const float4 xv = sxv[k4];
        const float* wp = wp0 + (size_t)k4 * 4 * F2;
        acc += xv.x * wp[0]      + xv.y * wp[F2]
             + xv.z * wp[2 * F2] + xv.w * wp[3 * F2];
    }
    acc += __shfl_xor(acc, 32);        // combine K halves; all lanes have h2[oc]

    float sA2 = acc * as2[oc], dA2 = acc * ad2[oc];
#pragma unroll
    for (int off = 1; off <= 16; off <<= 1) {
        sA2 += __shfl_xor(sA2, off);
        dA2 += __shfl_xor(dA2, off);
    }
    if (lane < 32) h2b[(size_t)wid * F2 + oc] = f2bf(acc);
    if (lane == 0) { s2[wid] = sA2; d2[wid] = dA2; }
}

// ---------------------------------------------------------------------------
// K_agg2: 4 lanes/edge (16 groups), uint4 loads, unroll x2 -> 32 gathers in
// flight; exp redundancy 4x. Fused log_softmax. Writes d_out.
// ---------------------------------------------------------------------------
__global__ __launch_bounds__(256) void k_agg2(
        const int* __restrict__ row_ptr, const int* __restrict__ srcs,
        const ushort* __restrict__ h2b, const float* __restrict__ s2,
        const float* __restrict__ d2, const float* __restrict__ b2,
        float* __restrict__ out) {
    const int wid = (blockIdx.x * 256 + threadIdx.x) >> 6;
    if (wid >= N_NODES) return;
    const int lane = threadIdx.x & 63;
    const int q = lane >> 2;          // edge group 0..15
    const int c = lane & 3;           // uint4 idx: channels 8c..8c+7
    const float dn = d2[wid];
    const int beg = row_ptr[wid], end = row_ptr[wid + 1];
    const uint4* hv = (const uint4*)h2b;      // 4 uint4 per node
    float a0 = 0.f, a1 = 0.f, a2 = 0.f, a3 = 0.f;
    float a4 = 0.f, a5 = 0.f, a6 = 0.f, a7 = 0.f, z = 0.f;
    int i = beg + q;
    for (; i + 16 < end; i += 32) {           // edges i, i+16
        const int sA = srcs[i], sB = srcs[i + 16];
        float eA = s2[sA] + dn;
        float eB = s2[sB] + dn;
        eA = eA > 0.f ? eA : SLOPE * eA;
        eB = eB > 0.f ? eB : SLOPE * eB;
        const float xA = __expf(eA), xB = __expf(eB);
        const uint4 UA = hv[(size_t)sA * 4 + c];
        const uint4 UB = hv[(size_t)sB * 4 + c];
        z  += xA + xB;
        a0 += xA * bflo(UA.x) + xB * bflo(UB.x);
        a1 += xA * bfhi(UA.x) + xB * bfhi(UB.x);
        a2 += xA * bflo(UA.y) + xB * bflo(UB.y);
        a3 += xA * bfhi(UA.y) + xB * bfhi(UB.y);
        a4 += xA * bflo(UA.z) + xB * bflo(UB.z);
        a5 += xA * bfhi(UA.z) + xB * bfhi(UB.z);
        a6 += xA * bflo(UA.w) + xB * bflo(UB.w);
        a7 += xA * bfhi(UA.w) + xB * bfhi(UB.w);
    }
    for (; i < end; i += 16) {
        const int sA = srcs[i];
        float eA = s2[sA] + dn;
        eA = eA > 0.f ? eA : SLOPE * eA;
        const float xA = __expf(eA);
        const uint4 UA = hv[(size_t)sA * 4 + c];
        z  += xA;
        a0 += xA * bflo(UA.x);
        a1 += xA * bfhi(UA.x);
        a2 += xA * bflo(UA.y);
        a3 += xA * bfhi(UA.y);
        a4 += xA * bflo(UA.z);
        a5 += xA * bfhi(UA.z);
        a6 += xA * bflo(UA.w);
        a7 += xA * bfhi(UA.w);
    }
#pragma unroll
    for (int off = 4; off <= 32; off <<= 1) {
        a0 += __shfl_xor(a0, off); a1 += __shfl_xor(a1, off);
        a2 += __shfl_xor(a2, off); a3 += __shfl_xor(a3, off);
        a4 += __shfl_xor(a4, off); a5 += __shfl_xor(a5, off);
        a6 += __shfl_xor(a6, off); a7 += __shfl_xor(a7, off);
        z  += __shfl_xor(z, off);
    }
    const float zi = 1.f / (z + 1e-16f);
    const float v0 = a0 * zi + b2[8 * c + 0];
    const float v1 = a1 * zi + b2[8 * c + 1];
    const float v2 = a2 * zi + b2[8 * c + 2];
    const float v3 = a3 * zi + b2[8 * c + 3];
    const float v4 = a4 * zi + b2[8 * c + 4];
    const float v5 = a5 * zi + b2[8 * c + 5];
    const float v6 = a6 * zi + b2[8 * c + 6];
    const float v7 = a7 * zi + b2[8 * c + 7];
    float m = fmaxf(fmaxf(fmaxf(v0, v1), fmaxf(v2, v3)),
                    fmaxf(fmaxf(v4, v5), fmaxf(v6, v7)));
#pragma unroll
    for (int off = 1; off <= 2; off <<= 1) m = fmaxf(m, __shfl_xor(m, off));
    float ssum = __expf(v0 - m) + __expf(v1 - m) + __expf(v2 - m) + __expf(v3 - m)
               + __expf(v4 - m) + __expf(v5 - m) + __expf(v6 - m) + __expf(v7 - m);
#pragma unroll
    for (int off = 1; off <= 2; off <<= 1) ssum += __shfl_xor(ssum, off);
    const float lse = m + __logf(ssum);
    if (lane < 4) {
        float4* o4 = (float4*)out;
        o4[(size_t)wid * 8 + 2 * c + 0] =
            make_float4(v0 - lse, v1 - lse, v2 - lse, v3 - lse);
        o4[(size_t)wid * 8 + 2 * c + 1] =
            make_float4(v4 - lse, v5 - lse, v6 - lse, v7 - lse);
    }
}

extern "C" void kernel_launch(void* const* d_in, const int* in_sizes, int n_in,
                              void* d_out, int out_size, void* d_ws, size_t ws_size,
                              hipStream_t stream) {
    const float* x   = (const float*)d_in[0];
    const int*   ei  = (const int*)d_in[1];
    const float* W1  = (const float*)d_in[2];
    const float* as1 = (const float*)d_in[3];
    const float* ad1 = (const float*)d_in[4];
    const float* b1  = (const float*)d_in[5];
    const float* W2  = (const float*)d_in[6];
    const float* as2 = (const float*)d_in[7];
    const float* ad2 = (const float*)d_in[8];
    const float* b2  = (const float*)d_in[9];
    float* out = (float*)d_out;

    // Workspace layout (no rank array; tmp int2 for counting sort)
    ushort* h1b = (ushort*)d_ws;                   // N*64 bf16
    ushort* h2b = h1b + (size_t)N_NODES * F1;      // N*32 bf16
    float*  s1  = (float*)(h2b + (size_t)N_NODES * F2);  // N*8
    float*  d1  = s1 + (size_t)N_NODES * H1;       // N*8
    float*  s2  = d1 + (size_t)N_NODES * H1;       // N
    float*  d2  = s2 + N_NODES;                    // N
    int2*   tmp = (int2*)(d2 + N_NODES);           // N_EDGES (8B aligned)
    int* cnt     = (int*)(tmp + N_EDGES);          // N
    int* row_ptr = cnt + N_NODES;                  // N+1
    int* bsum    = row_ptr + N_NODES + 1;          // 64
    int* colsum  = bsum + 64;                      // NBKT
    int* bcnt    = colsum + NBKT;                  // NBKT*NB1
    int* srcs    = bcnt + (size_t)NBKT * NB1;      // N_TOT

    const int nb_w = (N_NODES * 64 + 255) / 256;   // one wave per node

    k_gemm1_p1<<<NB_G + NB1, 256, 0, stream>>>(x, W1, as1, ad1, ei,
                                               h1b, s1, d1, bcnt);
    k_p2<<<NBKT, 64, 0, stream>>>(bcnt, colsum);
    k_p3<<<NB1, 256, 0, stream>>>(ei, bcnt, colsum, tmp);
    k_p4<<<NBKT, 256, 0, stream>>>(tmp, colsum, cnt);
    k_scan_a<<<NCH, 256, 0, stream>>>(cnt, row_ptr, bsum);
    k_scan_c2<<<(N_NODES + 256) / 256, 256, 0, stream>>>(row_ptr, bsum, srcs);
    k_p6<<<NBKT, 256, 0, stream>>>(tmp, colsum, row_ptr, srcs);
    k_agg1<<<nb_w, 256, 0, stream>>>(row_ptr, srcs, h1b, s1, d1, b1,
                                     W2, as2, ad2, h2b, s2, d2);
    k_agg2<<<nb_w, 256, 0, stream>>>(row_ptr, srcs, h2b, s2, d2, b2, out);
}

// Round 4
// 351.285 us; speedup vs baseline: 1.1385x; 1.0499x over previous
//
#include <hip/hip_runtime.h>
#include <hip/hip_bf16.h>

#define N_NODES 100000
#define N_EDGES 1600000
#define N_TOT   (N_EDGES + N_NODES)   // edges + self loops
#define F_IN    256
#define F1      64     // H1*C1
#define H1      8
#define C1      8
#define F2      32
#define SLOPE   0.2f
#define CHUNK   2048
#define NCH     ((N_NODES + CHUNK - 1) / CHUNK)   // 49

#define NB_G    ((N_NODES + 255) / 256)           // 391 gemm blocks

// counting-sort CSR build (no global atomics)
#define EB      4096                               // edges per P1/P3 block
#define NB1     ((N_EDGES + EB - 1) / EB)          // 391
#define BW      256                                // nodes per bucket
#define NBKT    ((N_NODES + BW - 1) / BW)          // 391

typedef unsigned int  uint;
typedef unsigned short ushort;
typedef __attribute__((ext_vector_type(8))) short bf16x8;
typedef __attribute__((ext_vector_type(4))) float f32x4;
typedef __attribute__((ext_vector_type(2))) float f32x2;

__device__ inline ushort f2bf(float f) {               // RNE float->bf16
    uint u = __float_as_uint(f);
    uint r = u + 0x7fffu + ((u >> 16) & 1u);
    return (ushort)(r >> 16);
}
__device__ inline float bflo(uint u) { return __uint_as_float(u << 16); }
__device__ inline float bfhi(uint u) { return __uint_as_float(u & 0xffff0000u); }
__device__ inline uint pk2bf(float a, float b) {
    __hip_bfloat162 h = __float22bfloat162_rn(make_float2(a, b));
    union { __hip_bfloat162 h; uint u; } cv; cv.h = h;
    return cv.u;
}

// Block-wide exclusive scan of colsum[NBKT] -> sb[0..NBKT] (sb[NBKT]=total).
// 256 threads; thread t owns elements 2t, 2t+1. sc = 256-int scratch.
__device__ inline void bucket_bases(const int* __restrict__ colsum,
                                    int* sc, int* sb, int tid) {
    const int i0 = 2 * tid, i1 = 2 * tid + 1;
    const int a0 = (i0 < NBKT) ? colsum[i0] : 0;
    const int a1 = (i1 < NBKT) ? colsum[i1] : 0;
    sc[tid] = a0 + a1;
    __syncthreads();
    for (int off = 1; off < 256; off <<= 1) {
        int t = (tid >= off) ? sc[tid - off] : 0;
        __syncthreads();
        sc[tid] += t;
        __syncthreads();
    }
    const int excl = sc[tid] - (a0 + a1);
    if (i0 < NBKT)  sb[i0] = excl;
    if (i1 <= NBKT) sb[i1] = excl + a0;       // writes sb[NBKT] (=total) too
    __syncthreads();
}

// ---------------------------------------------------------------------------
// K1 fused: blocks [0,NB_G) = MFMA gemm (h1 = x@W1 + s1/d1 dots);
// blocks [NB_G, NB_G+NB1) = P1 bucket-count over real edges (LDS histogram,
// plain stores to bcnt -- NO global atomics).
// ---------------------------------------------------------------------------
__global__ __launch_bounds__(256) void k_gemm1_p1(
        const float* __restrict__ x, const float* __restrict__ W1,
        const float* __restrict__ as1, const float* __restrict__ ad1,
        const int* __restrict__ ei,
        ushort* __restrict__ h1b, float* __restrict__ s1, float* __restrict__ d1,
        int* __restrict__ bcnt) {
    __shared__ union {
        ushort B[F_IN * F1];        // 32 KB: W1 bf16, idx = ((k>>3)*64+n)*8 + (k&7)
        ushort S[4][64][66];        // 33.8 KB: per-wave h staging (pad 66)
        int    H[NBKT];             // P1 histogram
    } sm;
    const int tid = threadIdx.x;

    if (blockIdx.x >= NB_G) {                      // ---- P1 bucket count ----
        const int blk = blockIdx.x - NB_G;
        for (int j = tid; j < NBKT; j += 256) sm.H[j] = 0;
        __syncthreads();
        const int e0 = blk * EB;
        const int lim = (e0 + EB < N_EDGES) ? e0 + EB : N_EDGES;
        for (int i = e0 + tid; i < lim; i += 256)
            atomicAdd(&sm.H[ei[N_EDGES + i] >> 8], 1);   // LDS atomic
        __syncthreads();
        for (int j = tid; j < NBKT; j += 256)
            bcnt[j * NB1 + blk] = sm.H[j];
        return;
    }

    // ---- MFMA gemm part ----
    for (int i = 0; i < 64; ++i) {                 // stage + swizzle W1
        const int e = i * 256 + tid;               // e = k*64 + n
        const int k = e >> 6, n = e & 63;
        sm.B[((k >> 3) * 64 + n) * 8 + (k & 7)] = f2bf(W1[e]);
    }
    __syncthreads();

    const int wave = tid >> 6, lane = tid & 63;
    const int q = lane >> 4, ln = lane & 15;
    const int rowbase = blockIdx.x * 256 + wave * 64;

    f32x4 acc[4][4];
#pragma unroll
    for (int mt = 0; mt < 4; ++mt)
#pragma unroll
        for (int nt = 0; nt < 4; ++nt) acc[mt][nt] = (f32x4){0.f, 0.f, 0.f, 0.f};

    int rows[4];
#pragma unroll
    for (int mt = 0; mt < 4; ++mt) {
        const int r = rowbase + mt * 16 + ln;
        rows[mt] = r < N_NODES ? r : N_NODES - 1;
    }

    for (int t = 0; t < 8; ++t) {                  // K-loop: 8 x 32
        bf16x8 bfr[4];
#pragma unroll
        for (int nt = 0; nt < 4; ++nt)
            bfr[nt] = *(const bf16x8*)&sm.B[((t * 4 + q) * 64 + nt * 16 + ln) * 8];
#pragma unroll
        for (int mt = 0; mt < 4; ++mt) {
            const float4* ap = (const float4*)(x + (size_t)rows[mt] * F_IN + t * 32 + q * 8);
            const float4 a0 = ap[0], a1 = ap[1];
            uint4 au = make_uint4(pk2bf(a0.x, a0.y), pk2bf(a0.z, a0.w),
                                  pk2bf(a1.x, a1.y), pk2bf(a1.z, a1.w));
            bf16x8 af = *(bf16x8*)&au;
#pragma unroll
            for (int nt = 0; nt < 4; ++nt)
                acc[mt][nt] = __builtin_amdgcn_mfma_f32_16x16x32_bf16(
                                  af, bfr[nt], acc[mt][nt], 0, 0, 0);
        }
    }
    __syncthreads();

    // stage h (bf16): C/D layout col=lane&15, row=q*4+r
#pragma unroll
    for (int mt = 0; mt < 4; ++mt)
#pragma unroll
        for (int nt = 0; nt < 4; ++nt)
#pragma unroll
            for (int r = 0; r < 4; ++r)
                sm.S[wave][mt * 16 + q * 4 + r][nt * 16 + ln] = f2bf(acc[mt][nt][r]);
    __syncthreads();

    const int node = rowbase + lane;
    if (node >= N_NODES) return;
    const uint* srow = (const uint*)&sm.S[wave][lane][0];
    float sacc[H1], dacc[H1];
#pragma unroll
    for (int h = 0; h < H1; ++h) { sacc[h] = 0.f; dacc[h] = 0.f; }
    uint4* hout = (uint4*)(h1b + (size_t)node * F1);
#pragma unroll
    for (int p4 = 0; p4 < 8; ++p4) {               // p4 == head index
        const uint u0 = srow[p4 * 4 + 0], u1 = srow[p4 * 4 + 1];
        const uint u2 = srow[p4 * 4 + 2], u3 = srow[p4 * 4 + 3];
        hout[p4] = make_uint4(u0, u1, u2, u3);
        const float c[8] = {bflo(u0), bfhi(u0), bflo(u1), bfhi(u1),
                            bflo(u2), bfhi(u2), bflo(u3), bfhi(u3)};
#pragma unroll
        for (int j = 0; j < 8; ++j) {
            sacc[p4] += c[j] * as1[p4 * 8 + j];
            dacc[p4] += c[j] * ad1[p4 * 8 + j];
        }
    }
    float4* s4 = (float4*)(s1 + (size_t)node * H1);
    float4* d4 = (float4*)(d1 + (size_t)node * H1);
    s4[0] = make_float4(sacc[0], sacc[1], sacc[2], sacc[3]);
    s4[1] = make_float4(sacc[4], sacc[5], sacc[6], sacc[7]);
    d4[0] = make_float4(dacc[0], dacc[1], dacc[2], dacc[3]);
    d4[1] = make_float4(dacc[4], dacc[5], dacc[6], dacc[7]);
}

// ---------------------------------------------------------------------------
// P2: per-bucket exclusive scan of bcnt[bucket][*] across blocks (in place)
// + column sums. One wave per bucket.
// ---------------------------------------------------------------------------
__global__ __launch_bounds__(64) void k_p2(
        int* __restrict__ bcnt, int* __restrict__ colsum) {
    const int col = blockIdx.x, lane = threadIdx.x;
    int carry = 0;
    for (int c0 = 0; c0 < NB1; c0 += 64) {
        const int idx = c0 + lane;
        const int v = (idx < NB1) ? bcnt[col * NB1 + idx] : 0;
        int s = v;
#pragma unroll
        for (int off = 1; off < 64; off <<= 1) {
            int u = __shfl_up(s, off);
            if (lane >= off) s += u;
        }
        if (idx < NB1) bcnt[col * NB1 + idx] = carry + s - v;
        carry += __shfl(s, 63);
    }
    if (lane == 0) colsum[col] = carry;
}

// ---------------------------------------------------------------------------
// P3: bucket scatter. Each block re-reads its EB edges, places (src,dst)
// into bucket-ordered tmp via LDS cursors = base[bucket] + myBlockOffset.
// ---------------------------------------------------------------------------
__global__ __launch_bounds__(256) void k_p3(
        const int* __restrict__ ei, const int* __restrict__ bcnt,
        const int* __restrict__ colsum, int2* __restrict__ tmp) {
    __shared__ int sc[256];
    __shared__ int cur[NBKT + 1];
    const int tid = threadIdx.x, blk = blockIdx.x;
    bucket_bases(colsum, sc, cur, tid);
    for (int b = tid; b < NBKT; b += 256) cur[b] += bcnt[b * NB1 + blk];
    __syncthreads();
    const int e0 = blk * EB;
    const int lim = (e0 + EB < N_EDGES) ? e0 + EB : N_EDGES;
    for (int i = e0 + tid; i < lim; i += 256) {
        const int s = ei[i], d = ei[N_EDGES + i];
        const int pos = atomicAdd(&cur[d >> 8], 1);     // LDS atomic
        tmp[pos] = make_int2(s, d);
    }
}

// ---------------------------------------------------------------------------
// P4: per-node counts. One block per bucket (256 nodes); LDS histogram over
// the bucket's tmp range; plain stores to cnt (no memset needed).
// ---------------------------------------------------------------------------
__global__ __launch_bounds__(256) void k_p4(
        const int2* __restrict__ tmp, const int* __restrict__ colsum,
        int* __restrict__ cnt) {
    __shared__ int sc[256];
    __shared__ int sb[NBKT + 1];
    __shared__ int h[BW];
    const int tid = threadIdx.x, b = blockIdx.x;
    bucket_bases(colsum, sc, sb, tid);
    h[tid] = 0;
    __syncthreads();
    const int lo = sb[b], hi = sb[b + 1];
    for (int i = lo + tid; i < hi; i += 256)
        atomicAdd(&h[tmp[i].y & (BW - 1)], 1);          // LDS atomic
    __syncthreads();
    const int n = b * BW + tid;
    if (n < N_NODES) cnt[n] = h[tid];
}

// ---------------------------------------------------------------------------
// Scan: per-chunk scan (a) with +1 per node (reserved self-loop slot), then
// fused chunk-prefix + add + self-loop emit (c2).
// ---------------------------------------------------------------------------
__global__ __launch_bounds__(256) void k_scan_a(
        const int* __restrict__ cnt, int* __restrict__ row_ptr,
        int* __restrict__ bsum) {
    __shared__ int sdata[256];
    const int tid = threadIdx.x;
    const int base = blockIdx.x * CHUNK + tid * 8;
    int v[8];
    int tot = 0;
#pragma unroll
    for (int j = 0; j < 8; ++j) {
        v[j] = (base + j < N_NODES) ? cnt[base + j] + 1 : 0;   // +1 = self loop
        tot += v[j];
    }
    sdata[tid] = tot;
    __syncthreads();
    for (int off = 1; off < 256; off <<= 1) {
        int t = (tid >= off) ? sdata[tid - off] : 0;
        __syncthreads();
        sdata[tid] += t;
        __syncthreads();
    }
    int run = sdata[tid] - tot;
#pragma unroll
    for (int j = 0; j < 8; ++j) {
        if (base + j < N_NODES) row_ptr[base + j] = run;
        run += v[j];
    }
    if (tid == 255) bsum[blockIdx.x] = sdata[255];
}

__global__ __launch_bounds__(256) void k_scan_c2(
        int* __restrict__ row_ptr, const int* __restrict__ bsum,
        int* __restrict__ srcs) {
    __shared__ int pb[64];
    const int t = threadIdx.x;
    if (t < 64) {                       // wave 0: exclusive prefix of bsum
        int v = (t < NCH) ? bsum[t] : 0;
        const int orig = v;
        for (int off = 1; off < 64; off <<= 1) {
            int u = __shfl_up(v, off);
            if (t >= off) v += u;
        }
        pb[t] = v - orig;
    }
    __syncthreads();
    const int i = blockIdx.x * 256 + t;
    if (i < N_NODES) {
        const int rp = row_ptr[i] + pb[i / CHUNK];
        row_ptr[i] = rp;
        srcs[rp] = i;                   // self loop occupies segment slot 0
    } else if (i == N_NODES) row_ptr[N_NODES] = N_TOT;
}

// ---------------------------------------------------------------------------
// P6: final placement. One block per bucket: LDS row_ptr + per-node cursors;
// real edges land at row_ptr[d] + 1 + rank (slot 0 = self loop).
// ---------------------------------------------------------------------------
__global__ __launch_bounds__(256) void k_p6(
        const int2* __restrict__ tmp, const int* __restrict__ colsum,
        const int* __restrict__ row_ptr, int* __restrict__ srcs) {
    __shared__ int sc[256];
    __shared__ int sb[NBKT + 1];
    __shared__ int rp[BW];
    __shared__ int cur[BW];
    const int tid = threadIdx.x, b = blockIdx.x;
    bucket_bases(colsum, sc, sb, tid);
    const int n = b * BW + tid;
    rp[tid] = (n < N_NODES) ? row_ptr[n] : 0;
    cur[tid] = 0;
    __syncthreads();
    const int lo = sb[b], hi = sb[b + 1];
    for (int i = lo + tid; i < hi; i += 256) {
        const int2 e = tmp[i];
        const int loc = e.y & (BW - 1);
        const int r = atomicAdd(&cur[loc], 1);          // LDS atomic
        srcs[rp[loc] + 1 + r] = e.x;
    }
}

// ---------------------------------------------------------------------------
// K_agg1 (+ fused node GEMM): 8 lanes/edge, lane = head, uint4 h1 loads,
// f32x2 (v_pk_fma_f32) accumulators. Epilogue uses a REDUCE-SCATTER
// (recursive halving over rep-lane bits 3,4,5) so each lane ends holding
// exactly one x2 channel -> all-lane elu (no divergent lane<8 section),
// 1 LDS write/lane, then the fused 64x32 W2 GEMM + s2/d2 dots.
// ---------------------------------------------------------------------------
__global__ __launch_bounds__(256) void k_agg1(
        const int* __restrict__ row_ptr, const int* __restrict__ srcs,
        const ushort* __restrict__ h1b, const float* __restrict__ s1,
        const float* __restrict__ d1, const float* __restrict__ b1,
        const float* __restrict__ W2, const float* __restrict__ as2,
        const float* __restrict__ ad2,
        ushort* __restrict__ h2b, float* __restrict__ s2,
        float* __restrict__ d2) {
    __shared__ float sx[4][64];                    // per-wave x2 row (f32)
    const int wid = (blockIdx.x * 256 + threadIdx.x) >> 6;
    if (wid >= N_NODES) return;
    const int w = threadIdx.x >> 6;
    const int lane = threadIdx.x & 63;
    const int q = lane >> 3;          // edge group 0..7
    const int c = lane & 7;           // head (= uint4 idx: channels 8c..8c+7)
    const float dh = d1[(size_t)wid * H1 + c];
    const int beg = row_ptr[wid], end = row_ptr[wid + 1];
    const uint4* hv = (const uint4*)h1b;      // 8 uint4 per node
    f32x2 A0 = {0.f, 0.f}, A1 = {0.f, 0.f}, A2 = {0.f, 0.f}, A3 = {0.f, 0.f};
    float z = 0.f;
    int i = beg + q;
    for (; i + 8 < end; i += 16) {            // edges i, i+8
        const int sA = srcs[i], sB = srcs[i + 8];
        float eA = s1[(size_t)sA * H1 + c] + dh;
        float eB = s1[(size_t)sB * H1 + c] + dh;
        eA = fmaxf(eA, SLOPE * eA);           // leaky (slope<1)
        eB = fmaxf(eB, SLOPE * eB);
        const float xA = __expf(eA), xB = __expf(eB);
        const uint4 UA = hv[(size_t)sA * 8 + c];
        const uint4 UB = hv[(size_t)sB * 8 + c];
        z += xA + xB;
        const f32x2 xa = {xA, xA}, xb = {xB, xB};
        A0 += xa * (f32x2){bflo(UA.x), bfhi(UA.x)};
        A1 += xa * (f32x2){bflo(UA.y), bfhi(UA.y)};
        A2 += xa * (f32x2){bflo(UA.z), bfhi(UA.z)};
        A3 += xa * (f32x2){bflo(UA.w), bfhi(UA.w)};
        A0 += xb * (f32x2){bflo(UB.x), bfhi(UB.x)};
        A1 += xb * (f32x2){bflo(UB.y), bfhi(UB.y)};
        A2 += xb * (f32x2){bflo(UB.z), bfhi(UB.z)};
        A3 += xb * (f32x2){bflo(UB.w), bfhi(UB.w)};
    }
    for (; i < end; i += 8) {
        const int sA = srcs[i];
        float eA = s1[(size_t)sA * H1 + c] + dh;
        eA = fmaxf(eA, SLOPE * eA);
        const float xA = __expf(eA);
        const uint4 UA = hv[(size_t)sA * 8 + c];
        z += xA;
        const f32x2 xa = {xA, xA};
        A0 += xa * (f32x2){bflo(UA.x), bfhi(UA.x)};
        A1 += xa * (f32x2){bflo(UA.y), bfhi(UA.y)};
        A2 += xa * (f32x2){bflo(UA.z), bfhi(UA.z)};
        A3 += xa * (f32x2){bflo(UA.w), bfhi(UA.w)};
    }
    // ---- reduce-scatter over rep bits 3,4,5: lane ends with channel j ----
    f32x2 r0, r1;
    {   // off=8: keep hi(A2,A3) if bit3 else lo(A0,A1); exchange non-kept
        const bool hi = lane & 8;
        f32x2 snd0 = hi ? A0 : A2, snd1 = hi ? A1 : A3;
        const f32x2 kp0 = hi ? A2 : A0, kp1 = hi ? A3 : A1;
        snd0.x = __shfl_xor(snd0.x, 8); snd0.y = __shfl_xor(snd0.y, 8);
        snd1.x = __shfl_xor(snd1.x, 8); snd1.y = __shfl_xor(snd1.y, 8);
        r0 = kp0 + snd0; r1 = kp1 + snd1;
    }
    {   // off=16: keep r1 if bit4 else r0
        const bool hi = lane & 16;
        f32x2 snd = hi ? r0 : r1;
        const f32x2 kp = hi ? r1 : r0;
        snd.x = __shfl_xor(snd.x, 16); snd.y = __shfl_xor(snd.y, 16);
        r0 = kp + snd;
    }
    float sv;
    {   // off=32: keep .y if bit5 else .x
        const bool hi = lane & 32;
        float snd = hi ? r0.x : r0.y;
        const float kp = hi ? r0.y : r0.x;
        snd = __shfl_xor(snd, 32);
        sv = kp + snd;
    }
    z += __shfl_xor(z, 8); z += __shfl_xor(z, 16); z += __shfl_xor(z, 32);

    const int j = (((lane >> 3) & 1) << 2) | (((lane >> 4) & 1) << 1)
                | ((lane >> 5) & 1);
    const int xi = c * 8 + j;                  // this lane's x2 element
    const float zi = 1.f / (z + 1e-16f);
    float xv = sv * zi + b1[xi];
    xv = xv > 0.f ? xv : __expf(xv) - 1.f;     // elu, all 64 lanes (1 each)
    sx[w][xi] = xv;                            // permutation: conflict-free
    // In-wave LDS RAW: DS ops execute in order per wave; wave_barrier stops
    // compile-time reordering. No __syncthreads needed (per-wave row).
    __builtin_amdgcn_wave_barrier();

    // fused node GEMM: h2[oc] = sum_k x2[k] * W2[k][oc]  (lane: kh half, oc)
    const int kh = lane >> 5;          // K half 0..1
    const int oc = lane & 31;          // output channel
    const float4* sxv = (const float4*)&sx[w][kh * 32];   // broadcast reads
    const float* wp0 = W2 + (size_t)(kh * 32) * F2 + oc;  // coalesced 128B/half
    float acc = 0.f;
#pragma unroll
    for (int k4 = 0; k4 < 8; ++k4) {
        const float4 xv4 = sxv[k4];
        const float* wp = wp0 + (size_t)k4 * 4 * F2;
        acc += xv4.x * wp[0]      + xv4.y * wp[F2]
             + xv4.z * wp[2 * F2] + xv4.w * wp[3 * F2];
    }
    acc += __shfl_xor(acc, 32);        // combine K halves; all lanes have h2[oc]

    float sA2 = acc * as2[oc], dA2 = acc * ad2[oc];
#pragma unroll
    for (int off = 1; off <= 16; off <<= 1) {
        sA2 += __shfl_xor(sA2, off);
        dA2 += __shfl_xor(dA2, off);
    }
    const float accp = __shfl_xor(acc, 1);     // partner channel (oc^1)
    if (lane < 32 && !(lane & 1))
        *(uint*)&h2b[(size_t)wid * F2 + oc] = pk2bf(acc, accp);
    if (lane == 0) { s2[wid] = sA2; d2[wid] = dA2; }
}

// ---------------------------------------------------------------------------
// K_agg2: 4 lanes/edge (16 groups), uint4 loads, f32x2 accumulators.
// Reduce-scatter over rep bits 2,3,4 (+ plain combine over bit5) leaves each
// lane holding ONE class logit (dup x2 across halves) -> softmax tail is
// 1 exp/lane + 5-round max/sum within each 32-lane half. Writes d_out.
// ---------------------------------------------------------------------------
__global__ __launch_bounds__(256) void k_agg2(
        const int* __restrict__ row_ptr, const int* __restrict__ srcs,
        const ushort* __restrict__ h2b, const float* __restrict__ s2,
        const float* __restrict__ d2, const float* __restrict__ b2,
        float* __restrict__ out) {
    const int wid = (blockIdx.x * 256 + threadIdx.x) >> 6;
    if (wid >= N_NODES) return;
    const int lane = threadIdx.x & 63;
    const int q = lane >> 2;          // edge group 0..15
    const int c = lane & 3;           // uint4 idx: channels 8c..8c+7
    const float dn = d2[wid];
    const int beg = row_ptr[wid], end = row_ptr[wid + 1];
    const uint4* hv = (const uint4*)h2b;      // 4 uint4 per node
    f32x2 A0 = {0.f, 0.f}, A1 = {0.f, 0.f}, A2 = {0.f, 0.f}, A3 = {0.f, 0.f};
    float z = 0.f;
    int i = beg + q;
    for (; i + 16 < end; i += 32) {           // edges i, i+16
        const int sA = srcs[i], sB = srcs[i + 16];
        float eA = s2[sA] + dn;
        float eB = s2[sB] + dn;
        eA = fmaxf(eA, SLOPE * eA);
        eB = fmaxf(eB, SLOPE * eB);
        const float xA = __expf(eA), xB = __expf(eB);
        const uint4 UA = hv[(size_t)sA * 4 + c];
        const uint4 UB = hv[(size_t)sB * 4 + c];
        z += xA + xB;
        const f32x2 xa = {xA, xA}, xb = {xB, xB};
        A0 += xa * (f32x2){bflo(UA.x), bfhi(UA.x)};
        A1 += xa * (f32x2){bflo(UA.y), bfhi(UA.y)};
        A2 += xa * (f32x2){bflo(UA.z), bfhi(UA.z)};
        A3 += xa * (f32x2){bflo(UA.w), bfhi(UA.w)};
        A0 += xb * (f32x2){bflo(UB.x), bfhi(UB.x)};
        A1 += xb * (f32x2){bflo(UB.y), bfhi(UB.y)};
        A2 += xb * (f32x2){bflo(UB.z), bfhi(UB.z)};
        A3 += xb * (f32x2){bflo(UB.w), bfhi(UB.w)};
    }
    for (; i < end; i += 16) {
        const int sA = srcs[i];
        float eA = s2[sA] + dn;
        eA = fmaxf(eA, SLOPE * eA);
        const float xA = __expf(eA);
        const uint4 UA = hv[(size_t)sA * 4 + c];
        z += xA;
        const f32x2 xa = {xA, xA};
        A0 += xa * (f32x2){bflo(UA.x), bfhi(UA.x)};
        A1 += xa * (f32x2){bflo(UA.y), bfhi(UA.y)};
        A2 += xa * (f32x2){bflo(UA.z), bfhi(UA.z)};
        A3 += xa * (f32x2){bflo(UA.w), bfhi(UA.w)};
    }
    // ---- reduce-scatter over rep bits 2,3,4; plain combine over bit5 ----
    f32x2 r0, r1;
    {
        const bool hi = lane & 4;
        f32x2 snd0 = hi ? A0 : A2, snd1 = hi ? A1 : A3;
        const f32x2 kp0 = hi ? A2 : A0, kp1 = hi ? A3 : A1;
        snd0.x = __shfl_xor(snd0.x, 4); snd0.y = __shfl_xor(snd0.y, 4);
        snd1.x = __shfl_xor(snd1.x, 4); snd1.y = __shfl_xor(snd1.y, 4);
        r0 = kp0 + snd0; r1 = kp1 + snd1;
    }
    {
        const bool hi = lane & 8;
        f32x2 snd = hi ? r0 : r1;
        const f32x2 kp = hi ? r1 : r0;
        snd.x = __shfl_xor(snd.x, 8); snd.y = __shfl_xor(snd.y, 8);
        r0 = kp + snd;
    }
    float sv;
    {
        const bool hi = lane & 16;
        float snd = hi ? r0.x : r0.y;
        const float kp = hi ? r0.y : r0.x;
        snd = __shfl_xor(snd, 16);
        sv = kp + snd;
    }
    sv += __shfl_xor(sv, 32);          // lanes l, l^32 now duplicate
    z += __shfl_xor(z, 4); z += __shfl_xor(z, 8);
    z += __shfl_xor(z, 16); z += __shfl_xor(z, 32);

    const int j = (((lane >> 2) & 1) << 2) | (((lane >> 3) & 1) << 1)
                | ((lane >> 4) & 1);
    const int elem = c * 8 + j;        // this lane's class (dup over bit5)
    const float zi = 1.f / (z + 1e-16f);
    const float v = sv * zi + b2[elem];
    // log-softmax over the 32 classes: each 32-lane half holds all 32 once.
    float m = v;
#pragma unroll
    for (int off = 1; off <= 16; off <<= 1) m = fmaxf(m, __shfl_xor(m, off));
    float ssum = __expf(v - m);
#pragma unroll
    for (int off = 1; off <= 16; off <<= 1) ssum += __shfl_xor(ssum, off);
    const float lse = m + __logf(ssum);
    if (lane < 32) out[(size_t)wid * F2 + elem] = v - lse;
}

extern "C" void kernel_launch(void* const* d_in, const int* in_sizes, int n_in,
                              void* d_out, int out_size, void* d_ws, size_t ws_size,
                              hipStream_t stream) {
    const float* x   = (const float*)d_in[0];
    const int*   ei  = (const int*)d_in[1];
    const float* W1  = (const float*)d_in[2];
    const float* as1 = (const float*)d_in[3];
    const float* ad1 = (const float*)d_in[4];
    const float* b1  = (const float*)d_in[5];
    const float* W2  = (const float*)d_in[6];
    const float* as2 = (const float*)d_in[7];
    const float* ad2 = (const float*)d_in[8];
    const float* b2  = (const float*)d_in[9];
    float* out = (float*)d_out;

    // Workspace layout (no rank array; tmp int2 for counting sort)
    ushort* h1b = (ushort*)d_ws;                   // N*64 bf16
    ushort* h2b = h1b + (size_t)N_NODES * F1;      // N*32 bf16
    float*  s1  = (float*)(h2b + (size_t)N_NODES * F2);  // N*8
    float*  d1  = s1 + (size_t)N_NODES * H1;       // N*8
    float*  s2  = d1 + (size_t)N_NODES * H1;       // N
    float*  d2  = s2 + N_NODES;                    // N
    int2*   tmp = (int2*)(d2 + N_NODES);           // N_EDGES (8B aligned)
    int* cnt     = (int*)(tmp + N_EDGES);          // N
    int* row_ptr = cnt + N_NODES;                  // N+1
    int* bsum    = row_ptr + N_NODES + 1;          // 64
    int* colsum  = bsum + 64;                      // NBKT
    int* bcnt    = colsum + NBKT;                  // NBKT*NB1
    int* srcs    = bcnt + (size_t)NBKT * NB1;      // N_TOT

    const int nb_w = (N_NODES * 64 + 255) / 256;   // one wave per node

    k_gemm1_p1<<<NB_G + NB1, 256, 0, stream>>>(x, W1, as1, ad1, ei,
                                               h1b, s1, d1, bcnt);
    k_p2<<<NBKT, 64, 0, stream>>>(bcnt, colsum);
    k_p3<<<NB1, 256, 0, stream>>>(ei, bcnt, colsum, tmp);
    k_p4<<<NBKT, 256, 0, stream>>>(tmp, colsum, cnt);
    k_scan_a<<<NCH, 256, 0, stream>>>(cnt, row_ptr, bsum);
    k_scan_c2<<<(N_NODES + 256) / 256, 256, 0, stream>>>(row_ptr, bsum, srcs);
    k_p6<<<NBKT, 256, 0, stream>>>(tmp, colsum, row_ptr, srcs);
    k_agg1<<<nb_w, 256, 0, stream>>>(row_ptr, srcs, h1b, s1, d1, b1,
                                     W2, as2, ad2, h2b, s2, d2);
    k_agg2<<<nb_w, 256, 0, stream>>>(row_ptr, srcs, h2b, s2, d2, b2, out);
}

// Round 5
// 342.152 us; speedup vs baseline: 1.1689x; 1.0267x over previous
//
#include <hip/hip_runtime.h>
#include <hip/hip_bf16.h>

#define N_NODES 100000
#define N_EDGES 1600000
#define N_TOT   (N_EDGES + N_NODES)   // edges + self loops
#define F_IN    256
#define F1      64     // H1*C1
#define H1      8
#define C1      8
#define F2      32
#define SLOPE   0.2f

#define NB_G    ((N_NODES + 255) / 256)           // 391 gemm blocks

// counting-sort CSR build (no global atomics)
#define EB      4096                               // edges per P1/P3 block
#define NB1     ((N_EDGES + EB - 1) / EB)          // 391
#define BW      256                                // nodes per bucket
#define NBKT    ((N_NODES + BW - 1) / BW)          // 391

typedef unsigned int  uint;
typedef unsigned short ushort;
typedef __attribute__((ext_vector_type(8))) short bf16x8;
typedef __attribute__((ext_vector_type(4))) float f32x4;
typedef __attribute__((ext_vector_type(2))) float f32x2;

__device__ inline ushort f2bf(float f) {               // RNE float->bf16
    uint u = __float_as_uint(f);
    uint r = u + 0x7fffu + ((u >> 16) & 1u);
    return (ushort)(r >> 16);
}
__device__ inline float bflo(uint u) { return __uint_as_float(u << 16); }
__device__ inline float bfhi(uint u) { return __uint_as_float(u & 0xffff0000u); }
__device__ inline uint pk2bf(float a, float b) {
    __hip_bfloat162 h = __float22bfloat162_rn(make_float2(a, b));
    union { __hip_bfloat162 h; uint u; } cv; cv.h = h;
    return cv.u;
}

// Block-wide exclusive scan of colsum[NBKT] -> sb[0..NBKT] (sb[NBKT]=total).
// 256 threads; thread t owns elements 2t, 2t+1. sc = 256-int scratch.
__device__ inline void bucket_bases(const int* __restrict__ colsum,
                                    int* sc, int* sb, int tid) {
    const int i0 = 2 * tid, i1 = 2 * tid + 1;
    const int a0 = (i0 < NBKT) ? colsum[i0] : 0;
    const int a1 = (i1 < NBKT) ? colsum[i1] : 0;
    sc[tid] = a0 + a1;
    __syncthreads();
    for (int off = 1; off < 256; off <<= 1) {
        int t = (tid >= off) ? sc[tid - off] : 0;
        __syncthreads();
        sc[tid] += t;
        __syncthreads();
    }
    const int excl = sc[tid] - (a0 + a1);
    if (i0 < NBKT)  sb[i0] = excl;
    if (i1 <= NBKT) sb[i1] = excl + a0;       // writes sb[NBKT] (=total) too
    __syncthreads();
}

// ---------------------------------------------------------------------------
// K1 fused: blocks [0,NB_G) = MFMA gemm (h1 = x@W1 + s1/d1 dots, written as
// 160B/node combined row: 8 f32 s + 64 bf16 h); blocks [NB_G, NB_G+NB1) =
// P1 bucket-count over real edges (LDS histogram, plain stores to bcnt).
// ---------------------------------------------------------------------------
__global__ __launch_bounds__(256) void k_gemm1_p1(
        const float* __restrict__ x, const float* __restrict__ W1,
        const float* __restrict__ as1, const float* __restrict__ ad1,
        const int* __restrict__ ei,
        uint* __restrict__ sh1, float* __restrict__ d1,
        int* __restrict__ bcnt) {
    __shared__ union {
        ushort B[F_IN * F1];        // 32 KB: W1 bf16, idx = ((k>>3)*64+n)*8 + (k&7)
        ushort S[4][64][66];        // 33.8 KB: per-wave h staging (pad 66)
        int    H[NBKT];             // P1 histogram
    } sm;
    const int tid = threadIdx.x;

    if (blockIdx.x >= NB_G) {                      // ---- P1 bucket count ----
        const int blk = blockIdx.x - NB_G;
        for (int j = tid; j < NBKT; j += 256) sm.H[j] = 0;
        __syncthreads();
        const int e0 = blk * EB;
        const int lim = (e0 + EB < N_EDGES) ? e0 + EB : N_EDGES;
        for (int i = e0 + tid; i < lim; i += 256)
            atomicAdd(&sm.H[ei[N_EDGES + i] >> 8], 1);   // LDS atomic
        __syncthreads();
        for (int j = tid; j < NBKT; j += 256)
            bcnt[j * NB1 + blk] = sm.H[j];
        return;
    }

    // ---- MFMA gemm part ----
    for (int i = 0; i < 64; ++i) {                 // stage + swizzle W1
        const int e = i * 256 + tid;               // e = k*64 + n
        const int k = e >> 6, n = e & 63;
        sm.B[((k >> 3) * 64 + n) * 8 + (k & 7)] = f2bf(W1[e]);
    }
    __syncthreads();

    const int wave = tid >> 6, lane = tid & 63;
    const int q = lane >> 4, ln = lane & 15;
    const int rowbase = blockIdx.x * 256 + wave * 64;

    f32x4 acc[4][4];
#pragma unroll
    for (int mt = 0; mt < 4; ++mt)
#pragma unroll
        for (int nt = 0; nt < 4; ++nt) acc[mt][nt] = (f32x4){0.f, 0.f, 0.f, 0.f};

    int rows[4];
#pragma unroll
    for (int mt = 0; mt < 4; ++mt) {
        const int r = rowbase + mt * 16 + ln;
        rows[mt] = r < N_NODES ? r : N_NODES - 1;
    }

    for (int t = 0; t < 8; ++t) {                  // K-loop: 8 x 32
        bf16x8 bfr[4];
#pragma unroll
        for (int nt = 0; nt < 4; ++nt)
            bfr[nt] = *(const bf16x8*)&sm.B[((t * 4 + q) * 64 + nt * 16 + ln) * 8];
#pragma unroll
        for (int mt = 0; mt < 4; ++mt) {
            const float4* ap = (const float4*)(x + (size_t)rows[mt] * F_IN + t * 32 + q * 8);
            const float4 a0 = ap[0], a1 = ap[1];
            uint4 au = make_uint4(pk2bf(a0.x, a0.y), pk2bf(a0.z, a0.w),
                                  pk2bf(a1.x, a1.y), pk2bf(a1.z, a1.w));
            bf16x8 af = *(bf16x8*)&au;
#pragma unroll
            for (int nt = 0; nt < 4; ++nt)
                acc[mt][nt] = __builtin_amdgcn_mfma_f32_16x16x32_bf16(
                                  af, bfr[nt], acc[mt][nt], 0, 0, 0);
        }
    }
    __syncthreads();

    // stage h (bf16): C/D layout col=lane&15, row=q*4+r
#pragma unroll
    for (int mt = 0; mt < 4; ++mt)
#pragma unroll
        for (int nt = 0; nt < 4; ++nt)
#pragma unroll
            for (int r = 0; r < 4; ++r)
                sm.S[wave][mt * 16 + q * 4 + r][nt * 16 + ln] = f2bf(acc[mt][nt][r]);
    __syncthreads();

    const int node = rowbase + lane;
    if (node >= N_NODES) return;
    const uint* srow = (const uint*)&sm.S[wave][lane][0];
    float sacc[H1], dacc[H1];
#pragma unroll
    for (int h = 0; h < H1; ++h) { sacc[h] = 0.f; dacc[h] = 0.f; }
    uint* rowp = sh1 + (size_t)node * 40;          // 160B combined row
#pragma unroll
    for (int p4 = 0; p4 < 8; ++p4) {               // p4 == head index
        const uint u0 = srow[p4 * 4 + 0], u1 = srow[p4 * 4 + 1];
        const uint u2 = srow[p4 * 4 + 2], u3 = srow[p4 * 4 + 3];
        ((uint4*)rowp)[2 + p4] = make_uint4(u0, u1, u2, u3);   // h at +32B
        const float c[8] = {bflo(u0), bfhi(u0), bflo(u1), bfhi(u1),
                            bflo(u2), bfhi(u2), bflo(u3), bfhi(u3)};
#pragma unroll
        for (int j = 0; j < 8; ++j) {
            sacc[p4] += c[j] * as1[p4 * 8 + j];
            dacc[p4] += c[j] * ad1[p4 * 8 + j];
        }
    }
    ((float4*)rowp)[0] = make_float4(sacc[0], sacc[1], sacc[2], sacc[3]);
    ((float4*)rowp)[1] = make_float4(sacc[4], sacc[5], sacc[6], sacc[7]);
    float4* d4 = (float4*)(d1 + (size_t)node * H1);
    d4[0] = make_float4(dacc[0], dacc[1], dacc[2], dacc[3]);
    d4[1] = make_float4(dacc[4], dacc[5], dacc[6], dacc[7]);
}

// ---------------------------------------------------------------------------
// P2: per-bucket exclusive scan of bcnt[bucket][*] across blocks (in place)
// + column sums. One wave per bucket.
// ---------------------------------------------------------------------------
__global__ __launch_bounds__(64) void k_p2(
        int* __restrict__ bcnt, int* __restrict__ colsum) {
    const int col = blockIdx.x, lane = threadIdx.x;
    int carry = 0;
    for (int c0 = 0; c0 < NB1; c0 += 64) {
        const int idx = c0 + lane;
        const int v = (idx < NB1) ? bcnt[col * NB1 + idx] : 0;
        int s = v;
#pragma unroll
        for (int off = 1; off < 64; off <<= 1) {
            int u = __shfl_up(s, off);
            if (lane >= off) s += u;
        }
        if (idx < NB1) bcnt[col * NB1 + idx] = carry + s - v;
        carry += __shfl(s, 63);
    }
    if (lane == 0) colsum[col] = carry;
}

// ---------------------------------------------------------------------------
// P3: bucket scatter. Each block re-reads its EB edges, places PACKED
// (dst&255)<<24 | src (src < 2^17) into bucket-ordered tmp via LDS cursors.
// 32-bit tmp halves the sort traffic vs the old int2.
// ---------------------------------------------------------------------------
__global__ __launch_bounds__(256) void k_p3(
        const int* __restrict__ ei, const int* __restrict__ bcnt,
        const int* __restrict__ colsum, uint* __restrict__ tmp) {
    __shared__ int sc[256];
    __shared__ int cur[NBKT + 1];
    const int tid = threadIdx.x, blk = blockIdx.x;
    bucket_bases(colsum, sc, cur, tid);
    for (int b = tid; b < NBKT; b += 256) cur[b] += bcnt[b * NB1 + blk];
    __syncthreads();
    const int e0 = blk * EB;
    const int lim = (e0 + EB < N_EDGES) ? e0 + EB : N_EDGES;
    for (int i = e0 + tid; i < lim; i += 256) {
        const int s = ei[i], d = ei[N_EDGES + i];
        const int pos = atomicAdd(&cur[d >> 8], 1);     // LDS atomic
        tmp[pos] = ((uint)(d & 255) << 24) | (uint)s;
    }
}

// ---------------------------------------------------------------------------
// K_final: one block per bucket. Replaces P4 + scan_a + scan_c2 + P6:
// bucket b's CSR segment starts at off_b = sb[b] + b*256 (each earlier
// bucket = its edges + 256 self loops; only the last bucket is partial),
// so row_ptr needs only a LOCAL 256-wide scan. Count (LDS), scan 1+cnt,
// write row_ptr + self-loop slot 0, then place edges via LDS cursors.
// The bucket's tmp slice (~18 KB) stays cache-hot between the two passes.
// ---------------------------------------------------------------------------
__global__ __launch_bounds__(256) void k_final(
        const uint* __restrict__ tmp, const int* __restrict__ colsum,
        int* __restrict__ row_ptr, int* __restrict__ srcs) {
    __shared__ int sc[256];
    __shared__ int sb[NBKT + 1];
    __shared__ int cur[BW];
    const int tid = threadIdx.x, b = blockIdx.x;
    bucket_bases(colsum, sc, sb, tid);
    cur[tid] = 0;
    __syncthreads();
    const int lo = sb[b], hi = sb[b + 1];
    for (int i = lo + tid; i < hi; i += 256)
        atomicAdd(&cur[tmp[i] >> 24], 1);               // LDS atomic
    __syncthreads();
    const int n = b * BW + tid;
    const int myc = cur[tid];
    const int v = (n < N_NODES) ? myc + 1 : 0;          // +1 = self loop
    sc[tid] = v;
    __syncthreads();
    for (int off = 1; off < 256; off <<= 1) {
        int t = (tid >= off) ? sc[tid - off] : 0;
        __syncthreads();
        sc[tid] += t;
        __syncthreads();
    }
    const int rp = sb[b] + b * BW + (sc[tid] - v);
    if (n < N_NODES) {
        row_ptr[n] = rp;
        srcs[rp] = n;                                   // self loop slot 0
    }
    if (b == NBKT - 1 && tid == 255) row_ptr[N_NODES] = N_TOT;
    cur[tid] = rp + 1;                                  // edge cursor
    __syncthreads();
    for (int i = lo + tid; i < hi; i += 256) {
        const uint u = tmp[i];
        const int pos = atomicAdd(&cur[u >> 24], 1);    // LDS atomic
        srcs[pos] = (int)(u & 0xFFFFFFu);
    }
}

// ---------------------------------------------------------------------------
// K_agg1 (+ fused node GEMM): 8 lanes/edge, lane = head, combined 160B row
// gather (one base address per edge: s at +4c, h uint4 at +32+16c), f32x2
// accumulators, reduce-scatter epilogue (each lane ends with one x2
// channel), then fused 64x32 W2 GEMM + s2/d2 dots.
// ---------------------------------------------------------------------------
__global__ __launch_bounds__(256) void k_agg1(
        const int* __restrict__ row_ptr, const int* __restrict__ srcs,
        const uint* __restrict__ sh1, const float* __restrict__ d1,
        const float* __restrict__ b1,
        const float* __restrict__ W2, const float* __restrict__ as2,
        const float* __restrict__ ad2,
        ushort* __restrict__ h2b, float* __restrict__ s2,
        float* __restrict__ d2) {
    __shared__ float sx[4][64];                    // per-wave x2 row (f32)
    const int wid = (blockIdx.x * 256 + threadIdx.x) >> 6;
    if (wid >= N_NODES) return;
    const int w = threadIdx.x >> 6;
    const int lane = threadIdx.x & 63;
    const int q = lane >> 3;          // edge group 0..7
    const int c = lane & 7;           // head
    const int so = 4 * c;             // byte offset of s in row
    const int ho = 32 + 16 * c;       // byte offset of this head's h uint4
    const float dh = d1[(size_t)wid * H1 + c];
    const int beg = row_ptr[wid], end = row_ptr[wid + 1];
    const char* base = (const char*)sh1;
    f32x2 A0 = {0.f, 0.f}, A1 = {0.f, 0.f}, A2 = {0.f, 0.f}, A3 = {0.f, 0.f};
    float z = 0.f;
    int i = beg + q;
    for (; i + 8 < end; i += 16) {            // edges i, i+8
        const int sA = srcs[i], sB = srcs[i + 8];
        const char* rA = base + (size_t)sA * 160;
        const char* rB = base + (size_t)sB * 160;
        float eA = *(const float*)(rA + so) + dh;
        float eB = *(const float*)(rB + so) + dh;
        eA = fmaxf(eA, SLOPE * eA);           // leaky (slope<1)
        eB = fmaxf(eB, SLOPE * eB);
        const float xA = __expf(eA), xB = __expf(eB);
        const uint4 UA = *(const uint4*)(rA + ho);
        const uint4 UB = *(const uint4*)(rB + ho);
        z += xA + xB;
        const f32x2 xa = {xA, xA}, xb = {xB, xB};
        A0 += xa * (f32x2){bflo(UA.x), bfhi(UA.x)};
        A1 += xa * (f32x2){bflo(UA.y), bfhi(UA.y)};
        A2 += xa * (f32x2){bflo(UA.z), bfhi(UA.z)};
        A3 += xa * (f32x2){bflo(UA.w), bfhi(UA.w)};
        A0 += xb * (f32x2){bflo(UB.x), bfhi(UB.x)};
        A1 += xb * (f32x2){bflo(UB.y), bfhi(UB.y)};
        A2 += xb * (f32x2){bflo(UB.z), bfhi(UB.z)};
        A3 += xb * (f32x2){bflo(UB.w), bfhi(UB.w)};
    }
    for (; i < end; i += 8) {
        const int sA = srcs[i];
        const char* rA = base + (size_t)sA * 160;
        float eA = *(const float*)(rA + so) + dh;
        eA = fmaxf(eA, SLOPE * eA);
        const float xA = __expf(eA);
        const uint4 UA = *(const uint4*)(rA + ho);
        z += xA;
        const f32x2 xa = {xA, xA};
        A0 += xa * (f32x2){bflo(UA.x), bfhi(UA.x)};
        A1 += xa * (f32x2){bflo(UA.y), bfhi(UA.y)};
        A2 += xa * (f32x2){bflo(UA.z), bfhi(UA.z)};
        A3 += xa * (f32x2){bflo(UA.w), bfhi(UA.w)};
    }
    // ---- reduce-scatter over rep bits 3,4,5: lane ends with channel j ----
    f32x2 r0, r1;
    {   // off=8
        const bool hi = lane & 8;
        f32x2 snd0 = hi ? A0 : A2, snd1 = hi ? A1 : A3;
        const f32x2 kp0 = hi ? A2 : A0, kp1 = hi ? A3 : A1;
        snd0.x = __shfl_xor(snd0.x, 8); snd0.y = __shfl_xor(snd0.y, 8);
        snd1.x = __shfl_xor(snd1.x, 8); snd1.y = __shfl_xor(snd1.y, 8);
        r0 = kp0 + snd0; r1 = kp1 + snd1;
    }
    {   // off=16
        const bool hi = lane & 16;
        f32x2 snd = hi ? r0 : r1;
        const f32x2 kp = hi ? r1 : r0;
        snd.x = __shfl_xor(snd.x, 16); snd.y = __shfl_xor(snd.y, 16);
        r0 = kp + snd;
    }
    float sv;
    {   // off=32
        const bool hi = lane & 32;
        float snd = hi ? r0.x : r0.y;
        const float kp = hi ? r0.y : r0.x;
        snd = __shfl_xor(snd, 32);
        sv = kp + snd;
    }
    z += __shfl_xor(z, 8); z += __shfl_xor(z, 16); z += __shfl_xor(z, 32);

    const int j = (((lane >> 3) & 1) << 2) | (((lane >> 4) & 1) << 1)
                | ((lane >> 5) & 1);
    const int xi = c * 8 + j;                  // this lane's x2 element
    const float zi = 1.f / (z + 1e-16f);
    float xv = sv * zi + b1[xi];
    xv = xv > 0.f ? xv : __expf(xv) - 1.f;     // elu, all 64 lanes (1 each)
    sx[w][xi] = xv;                            // permutation: conflict-free
    __builtin_amdgcn_wave_barrier();           // in-wave LDS RAW ordering

    // fused node GEMM: h2[oc] = sum_k x2[k] * W2[k][oc]  (lane: kh half, oc)
    const int kh = lane >> 5;          // K half 0..1
    const int oc = lane & 31;          // output channel
    const float4* sxv = (const float4*)&sx[w][kh * 32];   // broadcast reads
    const float* wp0 = W2 + (size_t)(kh * 32) * F2 + oc;  // coalesced 128B/half
    float acc = 0.f;
#pragma unroll
    for (int k4 = 0; k4 < 8; ++k4) {
        const float4 xv4 = sxv[k4];
        const float* wp = wp0 + (size_t)k4 * 4 * F2;
        acc += xv4.x * wp[0]      + xv4.y * wp[F2]
             + xv4.z * wp[2 * F2] + xv4.w * wp[3 * F2];
    }
    acc += __shfl_xor(acc, 32);        // combine K halves; all lanes have h2[oc]

    float sA2 = acc * as2[oc], dA2 = acc * ad2[oc];
#pragma unroll
    for (int off = 1; off <= 16; off <<= 1) {
        sA2 += __shfl_xor(sA2, off);
        dA2 += __shfl_xor(dA2, off);
    }
    const float accp = __shfl_xor(acc, 1);     // partner channel (oc^1)
    if (lane < 32 && !(lane & 1))
        *(uint*)&h2b[(size_t)wid * F2 + oc] = pk2bf(acc, accp);
    if (lane == 0) { s2[wid] = sA2; d2[wid] = dA2; }
}

// ---------------------------------------------------------------------------
// K_agg2: 4 lanes/edge (16 groups), uint4 loads, f32x2 accumulators,
// reduce-scatter epilogue -> 1 exp/lane softmax tail. Writes d_out.
// ---------------------------------------------------------------------------
__global__ __launch_bounds__(256) void k_agg2(
        const int* __restrict__ row_ptr, const int* __restrict__ srcs,
        const ushort* __restrict__ h2b, const float* __restrict__ s2,
        const float* __restrict__ d2, const float* __restrict__ b2,
        float* __restrict__ out) {
    const int wid = (blockIdx.x * 256 + threadIdx.x) >> 6;
    if (wid >= N_NODES) return;
    const int lane = threadIdx.x & 63;
    const int q = lane >> 2;          // edge group 0..15
    const int c = lane & 3;           // uint4 idx: channels 8c..8c+7
    const float dn = d2[wid];
    const int beg = row_ptr[wid], end = row_ptr[wid + 1];
    const uint4* hv = (const uint4*)h2b;      // 4 uint4 per node
    f32x2 A0 = {0.f, 0.f}, A1 = {0.f, 0.f}, A2 = {0.f, 0.f}, A3 = {0.f, 0.f};
    float z = 0.f;
    int i = beg + q;
    for (; i + 16 < end; i += 32) {           // edges i, i+16
        const int sA = srcs[i], sB = srcs[i + 16];
        float eA = s2[sA] + dn;
        float eB = s2[sB] + dn;
        eA = fmaxf(eA, SLOPE * eA);
        eB = fmaxf(eB, SLOPE * eB);
        const float xA = __expf(eA), xB = __expf(eB);
        const uint4 UA = hv[(size_t)sA * 4 + c];
        const uint4 UB = hv[(size_t)sB * 4 + c];
        z += xA + xB;
        const f32x2 xa = {xA, xA}, xb = {xB, xB};
        A0 += xa * (f32x2){bflo(UA.x), bfhi(UA.x)};
        A1 += xa * (f32x2){bflo(UA.y), bfhi(UA.y)};
        A2 += xa * (f32x2){bflo(UA.z), bfhi(UA.z)};
        A3 += xa * (f32x2){bflo(UA.w), bfhi(UA.w)};
        A0 += xb * (f32x2){bflo(UB.x), bfhi(UB.x)};
        A1 += xb * (f32x2){bflo(UB.y), bfhi(UB.y)};
        A2 += xb * (f32x2){bflo(UB.z), bfhi(UB.z)};
        A3 += xb * (f32x2){bflo(UB.w), bfhi(UB.w)};
    }
    for (; i < end; i += 16) {
        const int sA = srcs[i];
        float eA = s2[sA] + dn;
        eA = fmaxf(eA, SLOPE * eA);
        const float xA = __expf(eA);
        const uint4 UA = hv[(size_t)sA * 4 + c];
        z += xA;
        const f32x2 xa = {xA, xA};
        A0 += xa * (f32x2){bflo(UA.x), bfhi(UA.x)};
        A1 += xa * (f32x2){bflo(UA.y), bfhi(UA.y)};
        A2 += xa * (f32x2){bflo(UA.z), bfhi(UA.z)};
        A3 += xa * (f32x2){bflo(UA.w), bfhi(UA.w)};
    }
    // ---- reduce-scatter over rep bits 2,3,4; plain combine over bit5 ----
    f32x2 r0, r1;
    {
        const bool hi = lane & 4;
        f32x2 snd0 = hi ? A0 : A2, snd1 = hi ? A1 : A3;
        const f32x2 kp0 = hi ? A2 : A0, kp1 = hi ? A3 : A1;
        snd0.x = __shfl_xor(snd0.x, 4); snd0.y = __shfl_xor(snd0.y, 4);
        snd1.x = __shfl_xor(snd1.x, 4); snd1.y = __shfl_xor(snd1.y, 4);
        r0 = kp0 + snd0; r1 = kp1 + snd1;
    }
    {
        const bool hi = lane & 8;
        f32x2 snd = hi ? r0 : r1;
        const f32x2 kp = hi ? r1 : r0;
        snd.x = __shfl_xor(snd.x, 8); snd.y = __shfl_xor(snd.y, 8);
        r0 = kp + snd;
    }
    float sv;
    {
        const bool hi = lane & 16;
        float snd = hi ? r0.x : r0.y;
        const float kp = hi ? r0.y : r0.x;
        snd = __shfl_xor(snd, 16);
        sv = kp + snd;
    }
    sv += __shfl_xor(sv, 32);          // lanes l, l^32 now duplicate
    z += __shfl_xor(z, 4); z += __shfl_xor(z, 8);
    z += __shfl_xor(z, 16); z += __shfl_xor(z, 32);

    const int j = (((lane >> 2) & 1) << 2) | (((lane >> 3) & 1) << 1)
                | ((lane >> 4) & 1);
    const int elem = c * 8 + j;        // this lane's class (dup over bit5)
    const float zi = 1.f / (z + 1e-16f);
    const float v = sv * zi + b2[elem];
    // log-softmax over the 32 classes: each 32-lane half holds all 32 once.
    float m = v;
#pragma unroll
    for (int off = 1; off <= 16; off <<= 1) m = fmaxf(m, __shfl_xor(m, off));
    float ssum = __expf(v - m);
#pragma unroll
    for (int off = 1; off <= 16; off <<= 1) ssum += __shfl_xor(ssum, off);
    const float lse = m + __logf(ssum);
    if (lane < 32) out[(size_t)wid * F2 + elem] = v - lse;
}

extern "C" void kernel_launch(void* const* d_in, const int* in_sizes, int n_in,
                              void* d_out, int out_size, void* d_ws, size_t ws_size,
                              hipStream_t stream) {
    const float* x   = (const float*)d_in[0];
    const int*   ei  = (const int*)d_in[1];
    const float* W1  = (const float*)d_in[2];
    const float* as1 = (const float*)d_in[3];
    const float* ad1 = (const float*)d_in[4];
    const float* b1  = (const float*)d_in[5];
    const float* W2  = (const float*)d_in[6];
    const float* as2 = (const float*)d_in[7];
    const float* ad2 = (const float*)d_in[8];
    const float* b2  = (const float*)d_in[9];
    float* out = (float*)d_out;

    // Workspace layout
    uint*   sh1 = (uint*)d_ws;                     // N*40 uints (s f32x8 + h bf16x64)
    ushort* h2b = (ushort*)(sh1 + (size_t)N_NODES * 40);   // N*32 bf16
    float*  d1  = (float*)(h2b + (size_t)N_NODES * F2);    // N*8
    float*  s2  = d1 + (size_t)N_NODES * H1;       // N
    float*  d2  = s2 + N_NODES;                    // N
    uint*   tmp = (uint*)(d2 + N_NODES);           // N_EDGES (packed)
    int* row_ptr = (int*)(tmp + N_EDGES);          // N+1
    int* colsum  = row_ptr + N_NODES + 1;          // NBKT
    int* bcnt    = colsum + NBKT;                  // NBKT*NB1
    int* srcs    = bcnt + (size_t)NBKT * NB1;      // N_TOT

    const int nb_w = (N_NODES * 64 + 255) / 256;   // one wave per node

    k_gemm1_p1<<<NB_G + NB1, 256, 0, stream>>>(x, W1, as1, ad1, ei,
                                               sh1, d1, bcnt);
    k_p2<<<NBKT, 64, 0, stream>>>(bcnt, colsum);
    k_p3<<<NB1, 256, 0, stream>>>(ei, bcnt, colsum, tmp);
    k_final<<<NBKT, 256, 0, stream>>>(tmp, colsum, row_ptr, srcs);
    k_agg1<<<nb_w, 256, 0, stream>>>(row_ptr, srcs, sh1, d1, b1,
                                     W2, as2, ad2, h2b, s2, d2);
    k_agg2<<<nb_w, 256, 0, stream>>>(row_ptr, srcs, h2b, s2, d2, b2, out);
}